// Round 8
// baseline (820.369 us; speedup 1.0000x reference)
//
#include <hip/hip_runtime.h>
#include <hip/hip_fp16.h>
#include <stdint.h>

#define Nn 50000
#define Ee 1600000
#define Gg 64
#define TB 2048                       // edges per bin-tile
#define NTB ((Ee + TB - 1) / TB)      // 782
#define NBK ((Nn + 255) / 256)        // 196 coarse buckets (256 nodes each)

typedef _Float16 f16x2 __attribute__((ext_vector_type(2)));
typedef _Float16 f16x4 __attribute__((ext_vector_type(4)));
typedef float    f32x4v __attribute__((ext_vector_type(4)));
typedef unsigned u32x4v __attribute__((ext_vector_type(4)));

__device__ __forceinline__ float fdot2f(f16x2 a, f16x2 b, float c) {
#if __has_builtin(__builtin_amdgcn_fdot2)
    return __builtin_amdgcn_fdot2(a, b, c, false);
#else
    return fmaf((float)a[0], (float)b[0], fmaf((float)a[1], (float)b[1], c));
#endif
}

// ---------------- legacy CSR build (fallback modes only) ----------------
__global__ void k_hist(const int* __restrict__ ei, int* __restrict__ deg) {
    int e = blockIdx.x * blockDim.x + threadIdx.x;
    if (e < Ee) atomicAdd(&deg[ei[Ee + e]], 1);
}

__global__ void k_scan1(const int* __restrict__ deg, int* __restrict__ row_ptr,
                        int* __restrict__ bsum) {
    __shared__ int buf[256];
    int i = blockIdx.x * 256 + threadIdx.x;
    int v = (i < Nn) ? deg[i] : 0;
    buf[threadIdx.x] = v;
    __syncthreads();
    for (int off = 1; off < 256; off <<= 1) {
        int t = (threadIdx.x >= off) ? buf[threadIdx.x - off] : 0;
        __syncthreads();
        buf[threadIdx.x] += t;
        __syncthreads();
    }
    if (i < Nn) row_ptr[i + 1] = buf[threadIdx.x];
    if (threadIdx.x == 255) bsum[blockIdx.x] = buf[255];
}

__global__ void k_scan2(int* __restrict__ bsum, int nb) {
    __shared__ int buf[256];
    int v = (threadIdx.x < nb) ? bsum[threadIdx.x] : 0;
    buf[threadIdx.x] = v;
    __syncthreads();
    for (int off = 1; off < 256; off <<= 1) {
        int t = (threadIdx.x >= off) ? buf[threadIdx.x - off] : 0;
        __syncthreads();
        buf[threadIdx.x] += t;
        __syncthreads();
    }
    if (threadIdx.x < nb) bsum[threadIdx.x] = buf[threadIdx.x];
}

__global__ void k_scan3(int* __restrict__ row_ptr, const int* __restrict__ bsum) {
    int i = blockIdx.x * 256 + threadIdx.x;
    if (i > Nn) return;
    if (i == 0) { row_ptr[0] = 0; return; }
    int b = (i - 1) >> 8;
    if (b > 0) row_ptr[i] += bsum[b - 1];
}

__global__ void k_scatter(const int* __restrict__ ei, int* __restrict__ cursor,
                          int* __restrict__ src_perm, int* __restrict__ eperm) {
    int e = blockIdx.x * blockDim.x + threadIdx.x;
    if (e >= Ee) return;
    int dst = ei[Ee + e];
    int pos = atomicAdd(&cursor[dst], 1);
    src_perm[pos] = ei[e];
    eperm[pos] = e;
}

__global__ void k_easort(const float* __restrict__ ea, const int* __restrict__ eperm,
                         __half* __restrict__ ea_h) {
    long t = (long)blockIdx.x * blockDim.x + threadIdx.x;
    if (t >= (long)Ee * 4) return;
    long idx = t >> 2;
    int e = eperm[idx];
    float4 v = ((const float4*)ea)[(long)e * 4 + (t & 3)];
    __half2 lo = __floats2half2_rn(v.x, v.y);
    __half2 hi = __floats2half2_rn(v.z, v.w);
    ((__half2*)ea_h)[t * 2]     = lo;
    ((__half2*)ea_h)[t * 2 + 1] = hi;
}

// ---------------- zero-global-atomic CSR build (main path) ----------------
// Device atomics retire at ~12 G/s on MI355X (R0/R2: 1.6M atomics == ~134us
// regardless of store count). So: NO per-edge global atomics anywhere.

__global__ __launch_bounds__(256) void k_cnt(const int* __restrict__ ei,
                                             int* __restrict__ table) {
    __shared__ int hist[NBK];
    for (int i = threadIdx.x; i < NBK; i += 256) hist[i] = 0;
    __syncthreads();
    int e0 = blockIdx.x * TB;
    for (int i = threadIdx.x; i < TB; i += 256) {
        int e = e0 + i;
        if (e >= Ee) break;
        int d = __builtin_nontemporal_load(&ei[Ee + e]);
        atomicAdd(&hist[d >> 8], 1);             // LDS atomic
    }
    __syncthreads();
    for (int i = threadIdx.x; i < NBK; i += 256)
        table[i * NTB + blockIdx.x] = hist[i];   // column-major for per-bucket scan
}

__global__ __launch_bounds__(256) void k_colscan(int* __restrict__ table,
                                                 int* __restrict__ bktsz) {
    __shared__ int buf[1024];                    // NTB=782 <= 1024
    int c = blockIdx.x;
    for (int k = 0; k < 4; ++k) {
        int i = threadIdx.x + k * 256;
        buf[i] = (i < NTB) ? table[c * NTB + i] : 0;
    }
    __syncthreads();
    for (int off = 1; off < 1024; off <<= 1) {   // Hillis-Steele inclusive
        int v[4];
        for (int k = 0; k < 4; ++k) {
            int i = threadIdx.x + k * 256;
            v[k] = (i >= off) ? buf[i - off] : 0;
        }
        __syncthreads();
        for (int k = 0; k < 4; ++k) buf[threadIdx.x + k * 256] += v[k];
        __syncthreads();
    }
    for (int k = 0; k < 4; ++k) {
        int i = threadIdx.x + k * 256;
        if (i < NTB) table[c * NTB + i] = i ? buf[i - 1] : 0;  // exclusive
    }
    if (threadIdx.x == 0) bktsz[c] = buf[1023];
}

__global__ __launch_bounds__(256) void k_bktscan(const int* __restrict__ bktsz,
                                                 int* __restrict__ bktbase) {
    __shared__ int buf[256];
    int i = threadIdx.x;
    buf[i] = (i < NBK) ? bktsz[i] : 0;
    __syncthreads();
    for (int off = 1; off < 256; off <<= 1) {
        int v = (i >= off) ? buf[i - off] : 0;
        __syncthreads();
        buf[i] += v;
        __syncthreads();
    }
    if (i == 0) bktbase[0] = 0;
    if (i < NBK) bktbase[i + 1] = buf[i];
}

__global__ __launch_bounds__(256) void k_binfill(const int* __restrict__ ei,
                        const int* __restrict__ table, const int* __restrict__ bktbase,
                        unsigned long long* __restrict__ tmp) {
    __shared__ int off_s[NBK];
    __shared__ int cnt_s[NBK];
    for (int i = threadIdx.x; i < NBK; i += 256) {
        off_s[i] = table[i * NTB + blockIdx.x];
        cnt_s[i] = 0;
    }
    __syncthreads();
    int e0 = blockIdx.x * TB;
    for (int i = threadIdx.x; i < TB; i += 256) {
        int e = e0 + i;
        if (e >= Ee) break;
        int src = __builtin_nontemporal_load(&ei[e]);
        int dst = __builtin_nontemporal_load(&ei[Ee + e]);
        int b = dst >> 8;
        int r = atomicAdd(&cnt_s[b], 1);         // LDS atomic
        long pos = (long)bktbase[b] + off_s[b] + r;
        tmp[pos] = ((unsigned long long)(unsigned)dst << 37)
                 | ((unsigned long long)(unsigned)src << 21)
                 | (unsigned long long)(unsigned)e;
    }
}

// one block per bucket: LDS node-counts -> row_ptr, then place src DIRECTLY
// at final CSR positions AND fuse the ea row gather + fp16 convert (kills
// the eord array round-trip + the separate scatB2 pass). ea gather is NT
// (single-use random) so it doesn't pollute L2; writes land in the bucket's
// L2-resident span.
__global__ __launch_bounds__(256) void k_bktB(const unsigned long long* __restrict__ tmp,
                        const int* __restrict__ bktbase, int* __restrict__ row_ptr,
                        int* __restrict__ src_perm,
                        const float* __restrict__ ea, __half* __restrict__ ea_h) {
    __shared__ int cnt[256];
    __shared__ int sc[256];
    __shared__ int lro[256];
    int b = blockIdx.x, tid = threadIdx.x;
    cnt[tid] = 0;
    __syncthreads();
    int s = bktbase[b], t_end = bktbase[b + 1];
    for (int i = s + tid; i < t_end; i += 256)
        atomicAdd(&cnt[(int)(tmp[i] >> 37) & 255], 1);
    __syncthreads();
    sc[tid] = cnt[tid];
    __syncthreads();
    for (int off = 1; off < 256; off <<= 1) {
        int v = (tid >= off) ? sc[tid - off] : 0;
        __syncthreads();
        sc[tid] += v;
        __syncthreads();
    }
    lro[tid] = tid ? sc[tid - 1] : 0;            // exclusive local row offset
    cnt[tid] = 0;
    int n = b * 256 + tid;
    if (n < Nn) row_ptr[n] = s + lro[tid];
    if (b == NBK - 1 && tid == 0) row_ptr[Nn] = Ee;
    __syncthreads();
    for (int i = s + tid; i < t_end; i += 256) {
        unsigned long long p = tmp[i];
        int dn = (int)(p >> 37) & 255;
        int r = atomicAdd(&cnt[dn], 1);          // LDS atomic
        int pos = s + lro[dn] + r;
        src_perm[pos] = (int)((p >> 21) & 0xFFFFull);
        int e = (int)(p & 0x1FFFFFull);
        const f32x4v* er = (const f32x4v*)(ea + (size_t)e * 16);
        f32x4v v0 = __builtin_nontemporal_load(er);
        f32x4v v1 = __builtin_nontemporal_load(er + 1);
        f32x4v v2 = __builtin_nontemporal_load(er + 2);
        f32x4v v3 = __builtin_nontemporal_load(er + 3);
        __half2 h0 = __floats2half2_rn(v0[0], v0[1]), h1 = __floats2half2_rn(v0[2], v0[3]);
        __half2 h2 = __floats2half2_rn(v1[0], v1[1]), h3 = __floats2half2_rn(v1[2], v1[3]);
        __half2 h4 = __floats2half2_rn(v2[0], v2[1]), h5 = __floats2half2_rn(v2[2], v2[3]);
        __half2 h6 = __floats2half2_rn(v3[0], v3[1]), h7 = __floats2half2_rn(v3[2], v3[3]);
        u32x4v a = {*(unsigned*)&h0, *(unsigned*)&h1, *(unsigned*)&h2, *(unsigned*)&h3};
        u32x4v bb = {*(unsigned*)&h4, *(unsigned*)&h5, *(unsigned*)&h6, *(unsigned*)&h7};
        u32x4v* o = (u32x4v*)(ea_h + (size_t)pos * 16);  // 32B-aligned
        __builtin_nontemporal_store(a, o);
        __builtin_nontemporal_store(bb, o + 1);
    }
}

__global__ void k_gbound(const int* __restrict__ batch, int* __restrict__ gstart) {
    int n = blockIdx.x * blockDim.x + threadIdx.x;
    if (n >= Nn) return;
    int b = batch[n];
    if (n == 0) { for (int g = 0; g <= b; ++g) gstart[g] = 0; }
    else { int bp = batch[n - 1]; for (int g = bp + 1; g <= b; ++g) gstart[g] = n; }
    if (n == Nn - 1) { for (int g = b + 1; g <= Gg; ++g) gstart[g] = Nn; }
}

// ---------------- node kernels ----------------
__global__ __launch_bounds__(256) void k_encode(const float* __restrict__ x,
                         const float* __restrict__ Wn,
                         const float* __restrict__ bn, float* __restrict__ h) {
    __shared__ float sx[64 * 32];
    int base = blockIdx.x * 64;
    for (int i = threadIdx.x; i < 512; i += 256) {
        int off = i * 4, row = off >> 5;
        f32x4v v = (base + row < Nn)
            ? __builtin_nontemporal_load(&((const f32x4v*)x)[(base * 32 + off) >> 2])
            : (f32x4v){0.f, 0.f, 0.f, 0.f};
        ((f32x4v*)sx)[i] = v;
    }
    __syncthreads();
    int lane = threadIdx.x & 63, wv = threadIdx.x >> 6;
    float acc[16];
    float b = bn[lane];
#pragma unroll
    for (int nn = 0; nn < 16; ++nn) acc[nn] = b;
#pragma unroll 1
    for (int k0 = 0; k0 < 32; k0 += 4) {
        float w0 = Wn[(k0 + 0) * 64 + lane];
        float w1 = Wn[(k0 + 1) * 64 + lane];
        float w2 = Wn[(k0 + 2) * 64 + lane];
        float w3 = Wn[(k0 + 3) * 64 + lane];
#pragma unroll
        for (int nn = 0; nn < 16; ++nn) {
            int row = wv * 16 + nn;
            float4 hv = *(const float4*)&sx[row * 32 + k0];
            acc[nn] = fmaf(hv.x, w0, fmaf(hv.y, w1, fmaf(hv.z, w2, fmaf(hv.w, w3, acc[nn]))));
        }
    }
#pragma unroll
    for (int nn = 0; nn < 16; ++nn) {
        int n = base + wv * 16 + nn;
        if (n < Nn) h[(size_t)n * 64 + lane] = fmaxf(acc[nn], 0.f);
    }
}

// All 3 layers' Wqm/bqm (fp32) in one launch (block = layer).
__global__ void k_wqm3(const float* __restrict__ Wq_all, const float* __restrict__ bq_all,
                       const float* __restrict__ We_all, float* __restrict__ Wqm3,
                       float* __restrict__ bqm3) {
    int l = blockIdx.x;
    const float* Wq = Wq_all + l * 4096;
    const float* bq = bq_all + l * 64;
    const float* We = We_all + l * 1024;
    float* Wqm = Wqm3 + l * 4096;
    float* bqm = bqm3 + l * 64;
    for (int o = threadIdx.x; o < 64 * 64; o += 256) {
        int j = o >> 6, lp = o & 63, hh = lp >> 4, ii = lp & 15;
        float acc = 0.f;
#pragma unroll
        for (int c = 0; c < 16; ++c)
            acc += Wq[j * 64 + hh * 16 + c] * We[ii * 64 + hh * 16 + c];
        Wqm[o] = acc;
    }
    if (threadIdx.x < 64) {
        int hh = threadIdx.x >> 4, ii = threadIdx.x & 15;
        float acc = 0.f;
#pragma unroll
        for (int c = 0; c < 16; ++c)
            acc += bq[hh * 16 + c] * We[ii * 64 + hh * 16 + c];
        bqm[threadIdx.x] = acc;
    }
}

// Pack fp16 pair-interleaved weights: P[(k>>1)*128 + 2*col + (k&1)] = W[k][col].
// SC*log2e folded into Wq and Wqm. grid = 3 layers x 5 mats.
__global__ void k_pack(const float* __restrict__ Wq, const float* __restrict__ Wk,
                       const float* __restrict__ Wv, const float* __restrict__ Wqm3,
                       const float* __restrict__ Ws, __half* __restrict__ pw) {
    int l = blockIdx.x / 5, m = blockIdx.x % 5;
    const float SC = 0.25f * 1.4426950408889634f;  // 1/sqrt(C) * log2(e)
    const float* src;
    float sc = 1.f;
    if (m == 0)      { src = Wq + l * 4096;   sc = SC; }
    else if (m == 1) { src = Wk + l * 4096; }
    else if (m == 2) { src = Wv + l * 4096; }
    else if (m == 3) { src = Wqm3 + l * 4096; sc = SC; }
    else             { src = Ws + l * 4096; }
    __half* dst = pw + ((size_t)l * 5 + m) * 4096;
    for (int i = threadIdx.x; i < 4096; i += 256) {
        int k = i >> 6, c = i & 63;
        dst[(k >> 1) * 128 + 2 * c + (k & 1)] = __float2half_rn(src[i] * sc);
    }
}

// fdot2 5-in-1 GEMM: h staged fp16 in LDS, weights from packed fp16 pairs,
// v_dot2_f32_f16 accumulate. q,t stored fp16 (SC pre-folded).
__global__ __launch_bounds__(256) void k_qkvt2(const float* __restrict__ h,
                       const __half* __restrict__ pw,
                       const float* __restrict__ bq, const float* __restrict__ bk,
                       const float* __restrict__ bv, const float* __restrict__ bqm,
                       const float* __restrict__ bs,
                       __half* __restrict__ qn16, __half* __restrict__ kv,
                       __half* __restrict__ tq16, float* __restrict__ sn) {
    __shared__ __half sh[64 * 64];
    int base = blockIdx.x * 64;
    for (int i = threadIdx.x; i < 1024; i += 256) {
        int off = i * 4, row = off >> 6;
        f32x4v v = (base + row < Nn)
            ? __builtin_nontemporal_load(&((const f32x4v*)h)[((size_t)base * 64 + off) >> 2])
            : (f32x4v){0.f, 0.f, 0.f, 0.f};
        ((__half2*)sh)[i * 2]     = __floats2half2_rn(v[0], v[1]);
        ((__half2*)sh)[i * 2 + 1] = __floats2half2_rn(v[2], v[3]);
    }
    __syncthreads();
    int lane = threadIdx.x & 63, wv = threadIdx.x >> 6;
    const float SC = 0.25f * 1.4426950408889634f;
    const __half* Pq = pw;
    const __half* Pk = pw + 4096;
    const __half* Pv = pw + 8192;
    const __half* Pt = pw + 12288;
    const __half* Ps = pw + 16384;
    float aq[16], ak[16], av[16], at[16], as_[16];
    float _bq = bq[lane] * SC, _bk = bk[lane], _bv = bv[lane],
          _bt = bqm[lane] * SC, _bs = bs[lane];
#pragma unroll
    for (int nn = 0; nn < 16; ++nn) {
        aq[nn] = _bq; ak[nn] = _bk; av[nn] = _bv; at[nn] = _bt; as_[nn] = _bs;
    }
#pragma unroll 1
    for (int k0 = 0; k0 < 64; k0 += 4) {
        int pi = (k0 >> 1) * 128 + 2 * lane;
        f16x2 wq0 = *(const f16x2*)(Pq + pi), wq1 = *(const f16x2*)(Pq + pi + 128);
        f16x2 wk0 = *(const f16x2*)(Pk + pi), wk1 = *(const f16x2*)(Pk + pi + 128);
        f16x2 wv0 = *(const f16x2*)(Pv + pi), wv1 = *(const f16x2*)(Pv + pi + 128);
        f16x2 wt0 = *(const f16x2*)(Pt + pi), wt1 = *(const f16x2*)(Pt + pi + 128);
        f16x2 ws0 = *(const f16x2*)(Ps + pi), ws1 = *(const f16x2*)(Ps + pi + 128);
#pragma unroll
        for (int nn = 0; nn < 16; ++nn) {
            int row = wv * 16 + nn;
            f16x4 hv = *(const f16x4*)&sh[row * 64 + k0];
            f16x2 h01 = __builtin_shufflevector(hv, hv, 0, 1);
            f16x2 h23 = __builtin_shufflevector(hv, hv, 2, 3);
            aq[nn]  = fdot2f(h01, wq0, fdot2f(h23, wq1, aq[nn]));
            ak[nn]  = fdot2f(h01, wk0, fdot2f(h23, wk1, ak[nn]));
            av[nn]  = fdot2f(h01, wv0, fdot2f(h23, wv1, av[nn]));
            at[nn]  = fdot2f(h01, wt0, fdot2f(h23, wt1, at[nn]));
            as_[nn] = fdot2f(h01, ws0, fdot2f(h23, ws1, as_[nn]));
        }
    }
#pragma unroll
    for (int nn = 0; nn < 16; ++nn) {
        int n = base + wv * 16 + nn;
        if (n < Nn) {
            size_t o = (size_t)n * 64 + lane;
            qn16[o] = __float2half_rn(aq[nn]);
            tq16[o] = __float2half_rn(at[nn]);
            sn[o] = as_[nn];
            kv[(size_t)n * 128 + lane]      = __float2half_rn(ak[nn]);
            kv[(size_t)n * 128 + 64 + lane] = __float2half_rn(av[nn]);
        }
    }
}

// ---- edge pass v7: R6 structure (8-edge, best occupancy) + NT cache policy ----
// R5-R7 invariant: ~75us at FETCH~205MB regardless of VALU/unroll -> L2-miss
// service floor. Decomposition: ea_h 51MB + node streams ~45MB + kv misses
// ~110MB (410MB random kv demand, 12.8MB ws thrashed by single-use streams
// in 4MB/XCD L2). Fix: nontemporal on every single-use stream (x, q, t, sn,
// src_perm, h) so kv keeps the L2 -> higher hit rate -> floor moves.
__global__ __launch_bounds__(256) void k_layer7(float* __restrict__ h,
                      const __half* __restrict__ qn16, const __half* __restrict__ kv,
                      const __half* __restrict__ tq16, const float* __restrict__ sn,
                      const int* __restrict__ row_ptr, const int* __restrict__ src_perm,
                      const __half* __restrict__ eah, const float* __restrict__ We) {
    __shared__ float sWe[1024];
    __shared__ float tE[4][64];
    __shared__ float tV[4][64];
    for (int t = threadIdx.x; t < 1024; t += 256) sWe[t] = We[t];
    __syncthreads();
    int lane = threadIdx.x & 63, wv = threadIdx.x >> 6;
    int slot = lane >> 4, sl = lane & 15;
    int hh = lane >> 4;
    const int xoff = 4 * (sl & 3);                 // within-head x offset
#pragma unroll 1
    for (int j = 0; j < 4; ++j) {
        int n = blockIdx.x * 16 + wv * 4 + j;
        if (n >= Nn) break;                        // wave-uniform
        int beg = row_ptr[n], end = row_ptr[n + 1];
        f16x4 qv = __builtin_nontemporal_load((const f16x4*)(qn16 + (size_t)n * 64 + 4 * sl));
        f16x4 tv = __builtin_nontemporal_load((const f16x4*)(tq16 + (size_t)n * 64 + 4 * sl));
        f16x2 qa = __builtin_shufflevector(qv, qv, 0, 1);
        f16x2 qb = __builtin_shufflevector(qv, qv, 2, 3);
        f16x2 ta = __builtin_shufflevector(tv, tv, 0, 1);
        f16x2 tb = __builtin_shufflevector(tv, tv, 2, 3);
        float accd = 0.f;
        float4 accv = make_float4(0.f, 0.f, 0.f, 0.f);
        float4 acce = make_float4(0.f, 0.f, 0.f, 0.f);
        for (int idx = beg; idx < end; idx += 8) {
            int e0 = idx + slot, e1 = idx + 4 + slot;
            bool ok0 = e0 < end, ok1 = e1 < end;
            int i0 = ok0 ? e0 : beg, i1 = ok1 ? e1 : beg;
            int s0 = __builtin_nontemporal_load(&src_perm[i0]);
            int s1 = __builtin_nontemporal_load(&src_perm[i1]);
            f16x4 k0 = *(const f16x4*)(kv + (size_t)s0 * 128 + 4 * sl);
            f16x4 v0 = *(const f16x4*)(kv + (size_t)s0 * 128 + 64 + 4 * sl);
            f16x4 k1 = *(const f16x4*)(kv + (size_t)s1 * 128 + 4 * sl);
            f16x4 v1 = *(const f16x4*)(kv + (size_t)s1 * 128 + 64 + 4 * sl);
            f16x4 x0 = __builtin_nontemporal_load((const f16x4*)(eah + (size_t)i0 * 16 + xoff));
            f16x4 x1 = __builtin_nontemporal_load((const f16x4*)(eah + (size_t)i1 * 16 + xoff));
            // dot over this lane's 4 channels; init -6 => -24 after 4-lane reduce
            float a0 = fdot2f(qa, __builtin_shufflevector(k0, k0, 0, 1),
                       fdot2f(qb, __builtin_shufflevector(k0, k0, 2, 3),
                       fdot2f(ta, __builtin_shufflevector(x0, x0, 0, 1),
                       fdot2f(tb, __builtin_shufflevector(x0, x0, 2, 3), -6.0f))));
            float a1 = fdot2f(qa, __builtin_shufflevector(k1, k1, 0, 1),
                       fdot2f(qb, __builtin_shufflevector(k1, k1, 2, 3),
                       fdot2f(ta, __builtin_shufflevector(x1, x1, 0, 1),
                       fdot2f(tb, __builtin_shufflevector(x1, x1, 2, 3), -6.0f))));
            a0 += __shfl_xor(a0, 1, 4); a1 += __shfl_xor(a1, 1, 4);
            a0 += __shfl_xor(a0, 2, 4); a1 += __shfl_xor(a1, 2, 4);
            float p0 = ok0 ? __builtin_exp2f(a0) : 0.f;
            float p1 = ok1 ? __builtin_exp2f(a1) : 0.f;
            accd += p0 + p1;
            accv.x = fmaf(p0, (float)v0[0], fmaf(p1, (float)v1[0], accv.x));
            accv.y = fmaf(p0, (float)v0[1], fmaf(p1, (float)v1[1], accv.y));
            accv.z = fmaf(p0, (float)v0[2], fmaf(p1, (float)v1[2], accv.z));
            accv.w = fmaf(p0, (float)v0[3], fmaf(p1, (float)v1[3], accv.w));
            acce.x = fmaf(p0, (float)x0[0], fmaf(p1, (float)x1[0], acce.x));
            acce.y = fmaf(p0, (float)x0[1], fmaf(p1, (float)x1[1], acce.y));
            acce.z = fmaf(p0, (float)x0[2], fmaf(p1, (float)x1[2], acce.z));
            acce.w = fmaf(p0, (float)x0[3], fmaf(p1, (float)x1[3], acce.w));
        }
        // merge the 4 independent slots (shared fixed shift -> plain adds)
        accd   += __shfl_xor(accd, 16);   accd   += __shfl_xor(accd, 32);
        accv.x += __shfl_xor(accv.x, 16); accv.x += __shfl_xor(accv.x, 32);
        accv.y += __shfl_xor(accv.y, 16); accv.y += __shfl_xor(accv.y, 32);
        accv.z += __shfl_xor(accv.z, 16); accv.z += __shfl_xor(accv.z, 32);
        accv.w += __shfl_xor(accv.w, 16); accv.w += __shfl_xor(accv.w, 32);
        acce.x += __shfl_xor(acce.x, 16); acce.x += __shfl_xor(acce.x, 32);
        acce.y += __shfl_xor(acce.y, 16); acce.y += __shfl_xor(acce.y, 32);
        acce.z += __shfl_xor(acce.z, 16); acce.z += __shfl_xor(acce.z, 32);
        acce.w += __shfl_xor(acce.w, 16); acce.w += __shfl_xor(acce.w, 32);
        float inv = 1.f / (accd + 1e-16f);
        if (slot == 0) {
            ((float4*)tE[wv])[sl] = make_float4(acce.x * inv, acce.y * inv,
                                                acce.z * inv, acce.w * inv);
            ((float4*)tV[wv])[sl] = make_float4(accv.x * inv, accv.y * inv,
                                                accv.z * inv, accv.w * inv);
        }
        // wave-lockstep LDS round-trip (same wave wrote it; no barrier)
        float re = 0.f;
#pragma unroll
        for (int i = 0; i < 16; ++i)
            re = fmaf(tE[wv][hh * 16 + i], sWe[i * 64 + lane], re);
        size_t o = (size_t)n * 64 + lane;
        float hv = __builtin_nontemporal_load(&h[o]);
        float s  = __builtin_nontemporal_load(&sn[o]);
        __builtin_nontemporal_store(hv + fmaxf(tV[wv][lane] + re + s, 0.f), &h[o]);
    }
}

// legacy edge pass (fallback mode 0 only: fp32 ea gather via eperm).
__global__ __launch_bounds__(256) void k_layer(float* __restrict__ h,
                      const __half* __restrict__ qn16, const __half* __restrict__ kv,
                      const __half* __restrict__ tq16, const float* __restrict__ sn,
                      const int* __restrict__ row_ptr, const int* __restrict__ src_perm,
                      const int* __restrict__ eperm, const float* __restrict__ eaf,
                      const float* __restrict__ We) {
    __shared__ float sWe[1024];
    __shared__ float tile[4][64];
    for (int t = threadIdx.x; t < 1024; t += 256) sWe[t] = We[t];
    __syncthreads();
    int lane = threadIdx.x & 63, wv = threadIdx.x >> 6;
    int hh = lane >> 4, cc = lane & 15;
    int n = blockIdx.x * 4 + wv;
    if (n >= Nn) return;
    int beg = row_ptr[n], end = row_ptr[n + 1];
    float q = __half2float(qn16[(size_t)n * 64 + lane]);
    float t = __half2float(tq16[(size_t)n * 64 + lane]);
    float m = -INFINITY, accd = 0.f, accv = 0.f, acce = 0.f;
    int idx = beg;
    for (; idx < end; ++idx) {
        long b0 = (long)src_perm[idx] * 128;
        float k0 = __half2float(kv[b0 + lane]);
        float v0 = __half2float(kv[b0 + 64 + lane]);
        float x0 = eaf[(long)eperm[idx] * 16 + cc];
        float a0 = fmaf(q, k0, x0 * t);
        a0 += __shfl_xor(a0, 1, 16);
        a0 += __shfl_xor(a0, 2, 16);
        a0 += __shfl_xor(a0, 4, 16);
        a0 += __shfl_xor(a0, 8, 16);
        float nm = fmaxf(m, a0);
        float w = __builtin_exp2f(m - nm);
        float p0 = __builtin_exp2f(a0 - nm);
        accd = fmaf(accd, w, p0);
        accv = fmaf(accv, w, p0 * v0);
        acce = fmaf(acce, w, p0 * x0);
        m = nm;
    }
    float inv = 1.f / (accd + 1e-16f);
    tile[wv][lane] = acce * inv;
    float re = 0.f;
#pragma unroll
    for (int i = 0; i < 16; ++i)
        re = fmaf(tile[wv][hh * 16 + i], sWe[i * 64 + lane], re);
    size_t o = (size_t)n * 64 + lane;
    float hv = h[o];
    h[o] = hv + fmaxf(fmaf(accv, inv, re + sn[o]), 0.f);
}

__global__ void k_pool(const float* __restrict__ h, const int* __restrict__ gstart,
                       const float* __restrict__ W1, const float* __restrict__ b1,
                       const float* __restrict__ W2, const float* __restrict__ b2,
                       float* __restrict__ out) {
    int g = blockIdx.x;
    int lane = threadIdx.x & 63, wv = threadIdx.x >> 6;
    int beg = gstart[g], end = gstart[g + 1];
    __shared__ float red[4][64];
    __shared__ float sp[64];
    __shared__ float sh[32];
    float acc = 0.f;
    for (int n = beg + wv; n < end; n += 4)
        acc += __builtin_nontemporal_load(&h[(size_t)n * 64 + lane]);
    red[wv][lane] = acc;
    __syncthreads();
    if (threadIdx.x < 64) {
        float c = fmaxf((float)(end - beg), 1.f);
        sp[lane] = (red[0][lane] + red[1][lane] + red[2][lane] + red[3][lane]) / c;
    }
    __syncthreads();
    if (threadIdx.x < 32) {
        int t = threadIdx.x;
        float a = b1[t];
#pragma unroll
        for (int i = 0; i < 64; ++i) a = fmaf(sp[i], W1[i * 32 + t], a);
        sh[t] = fmaxf(a, 0.f) * W2[t];
    }
    __syncthreads();
    if (threadIdx.x == 0) {
        float s = b2[0];
#pragma unroll
        for (int i = 0; i < 32; ++i) s += sh[i];
        out[g] = s;
    }
}

extern "C" void kernel_launch(void* const* d_in, const int* in_sizes, int n_in,
                              void* d_out, int out_size, void* d_ws, size_t ws_size,
                              hipStream_t stream) {
    const float* x   = (const float*)d_in[0];
    const int*   ei  = (const int*)d_in[1];
    const float* ea  = (const float*)d_in[2];
    const int*   bat = (const int*)d_in[3];
    const float* Wn  = (const float*)d_in[4];
    const float* bn  = (const float*)d_in[5];
    const float* Wq  = (const float*)d_in[6];
    const float* bq  = (const float*)d_in[7];
    const float* Wk  = (const float*)d_in[8];
    const float* bk  = (const float*)d_in[9];
    const float* Wv  = (const float*)d_in[10];
    const float* bv  = (const float*)d_in[11];
    const float* We  = (const float*)d_in[12];
    const float* Wsk = (const float*)d_in[13];
    const float* bs  = (const float*)d_in[14];
    const float* W1  = (const float*)d_in[15];
    const float* b1  = (const float*)d_in[16];
    const float* W2  = (const float*)d_in[17];
    const float* b2  = (const float*)d_in[18];
    float* out = (float*)d_out;

    const size_t NH = (size_t)Nn * 64;
    float* h    = (float*)d_ws;
    float* qn   = h + NH;                      // fp16 q (uses half the slot)
    float* tq   = h + 2 * NH;                  // fp16 t
    float* sn   = h + 3 * NH;
    __half* kv  = (__half*)(h + 4 * NH);       // N*128 half == NH floats of space
    float* Wqm3 = h + 5 * NH;                  // 3*4096
    float* bqm3 = Wqm3 + 3 * 4096;             // 3*64
    __half* pw  = (__half*)(bqm3 + 3 * 64);    // 3*5*4096 packed fp16 weights
    int* deg       = (int*)(pw + 3 * 5 * 4096);   // N (legacy)
    int* row_ptr   = deg + Nn;                 // N+1
    int* cursor    = row_ptr + Nn + 1;         // N (legacy)
    int* src_perm  = cursor + Nn;              // E
    int* eperm     = src_perm + Ee;            // E (legacy fallback only)
    int* bsum      = eperm + Ee;               // 256 (legacy)
    int* gstart    = bsum + 256;               // G+1
    char* pe = (char*)(gstart + Gg + 1);
    __half* ea_h = (__half*)(((uintptr_t)pe + 63) & ~(uintptr_t)63);   // E*16 half
    char* pt = (char*)(ea_h + (size_t)Ee * 16);
    unsigned long long* tmp =
        (unsigned long long*)(((uintptr_t)pt + 15) & ~(uintptr_t)15);  // E u64
    size_t need_eah = ((char*)(ea_h + (size_t)Ee * 16)) - (char*)d_ws;
    size_t need_tmp = ((char*)(tmp + Ee)) - (char*)d_ws;
    // CSR-build scratch overlaid on tq/sn (dead until k_qkvt2, and the
    // CSR build fully completes before k_qkvt2 in stream order):
    int* table   = (int*)tq;                             // NBK*NTB ints (~613 KB)
    int* bktsz   = (int*)sn;                             // NBK
    int* bktbase = bktsz + 256;                          // NBK+1
    __half* qn16 = (__half*)qn;
    __half* tq16 = (__half*)tq;
    // mode 2: zero-global-atomic counting-sort CSR build (fast).
    // mode 1: legacy scatter + easort. mode 0: legacy scatter, fp32 ea gather.
    int mode = (ws_size >= need_tmp) ? 2 : (ws_size >= need_eah) ? 1 : 0;

    if (mode == 2) {
        k_cnt<<<NTB, 256, 0, stream>>>(ei, table);
        k_colscan<<<NBK, 256, 0, stream>>>(table, bktsz);
        k_bktscan<<<1, 256, 0, stream>>>(bktsz, bktbase);
        k_binfill<<<NTB, 256, 0, stream>>>(ei, table, bktbase, tmp);
        k_bktB<<<NBK, 256, 0, stream>>>(tmp, bktbase, row_ptr, src_perm, ea, ea_h);
    } else {
        const int NB = 196;  // ceil(50000/256)
        hipMemsetAsync(deg, 0, Nn * sizeof(int), stream);
        k_hist<<<(Ee + 255) / 256, 256, 0, stream>>>(ei, deg);
        k_scan1<<<NB, 256, 0, stream>>>(deg, row_ptr, bsum);
        k_scan2<<<1, 256, 0, stream>>>(bsum, NB);
        k_scan3<<<(Nn + 256) / 256, 256, 0, stream>>>(row_ptr, bsum);
        hipMemcpyAsync(cursor, row_ptr, Nn * sizeof(int), hipMemcpyDeviceToDevice, stream);
        k_scatter<<<(Ee + 255) / 256, 256, 0, stream>>>(ei, cursor, src_perm, eperm);
        if (mode == 1)
            k_easort<<<((long)Ee * 4 + 255) / 256, 256, 0, stream>>>(ea, eperm, ea_h);
    }
    k_gbound<<<(Nn + 255) / 256, 256, 0, stream>>>(bat, gstart);
    k_wqm3<<<3, 256, 0, stream>>>(Wq, bq, We, Wqm3, bqm3);
    k_pack<<<15, 256, 0, stream>>>(Wq, Wk, Wv, Wqm3, Wsk, pw);

    int nodeBlocks = (Nn + 63) / 64;
    k_encode<<<nodeBlocks, 256, 0, stream>>>(x, Wn, bn, h);
    for (int l = 0; l < 3; ++l) {
        k_qkvt2<<<nodeBlocks, 256, 0, stream>>>(h, pw + (size_t)l * 5 * 4096,
                                                bq + l * 64, bk + l * 64, bv + l * 64,
                                                bqm3 + l * 64, bs + l * 64,
                                                qn16, kv, tq16, sn);
        if (mode >= 1)
            k_layer7<<<(Nn + 15) / 16, 256, 0, stream>>>(h, qn16, kv, tq16, sn,
                    row_ptr, src_perm, ea_h, We + l * 1024);
        else
            k_layer<<<(Nn + 3) / 4, 256, 0, stream>>>(h, qn16, kv, tq16, sn,
                    row_ptr, src_perm, eperm, ea, We + l * 1024);
    }
    k_pool<<<Gg, 256, 0, stream>>>(h, gstart, W1, b1, W2, b2, out);
}

// Round 9
// 683.480 us; speedup vs baseline: 1.2003x; 1.2003x over previous
//
#include <hip/hip_runtime.h>
#include <hip/hip_fp16.h>
#include <stdint.h>

#define Nn 50000
#define Ee 1600000
#define Gg 64
#define TB 2048                       // edges per bin-tile
#define NTB ((Ee + TB - 1) / TB)      // 782
#define NBK ((Nn + 255) / 256)        // 196 coarse buckets (256 nodes each)

typedef _Float16 f16x2 __attribute__((ext_vector_type(2)));
typedef _Float16 f16x4 __attribute__((ext_vector_type(4)));
typedef _Float16 f16x8 __attribute__((ext_vector_type(8)));
typedef float    f32x4v __attribute__((ext_vector_type(4)));

__device__ __forceinline__ float fdot2f(f16x2 a, f16x2 b, float c) {
#if __has_builtin(__builtin_amdgcn_fdot2)
    return __builtin_amdgcn_fdot2(a, b, c, false);
#else
    return fmaf((float)a[0], (float)b[0], fmaf((float)a[1], (float)b[1], c));
#endif
}

// ---------------- legacy CSR build (fallback modes only) ----------------
__global__ void k_hist(const int* __restrict__ ei, int* __restrict__ deg) {
    int e = blockIdx.x * blockDim.x + threadIdx.x;
    if (e < Ee) atomicAdd(&deg[ei[Ee + e]], 1);
}

__global__ void k_scan1(const int* __restrict__ deg, int* __restrict__ row_ptr,
                        int* __restrict__ bsum) {
    __shared__ int buf[256];
    int i = blockIdx.x * 256 + threadIdx.x;
    int v = (i < Nn) ? deg[i] : 0;
    buf[threadIdx.x] = v;
    __syncthreads();
    for (int off = 1; off < 256; off <<= 1) {
        int t = (threadIdx.x >= off) ? buf[threadIdx.x - off] : 0;
        __syncthreads();
        buf[threadIdx.x] += t;
        __syncthreads();
    }
    if (i < Nn) row_ptr[i + 1] = buf[threadIdx.x];
    if (threadIdx.x == 255) bsum[blockIdx.x] = buf[255];
}

__global__ void k_scan2(int* __restrict__ bsum, int nb) {
    __shared__ int buf[256];
    int v = (threadIdx.x < nb) ? bsum[threadIdx.x] : 0;
    buf[threadIdx.x] = v;
    __syncthreads();
    for (int off = 1; off < 256; off <<= 1) {
        int t = (threadIdx.x >= off) ? buf[threadIdx.x - off] : 0;
        __syncthreads();
        buf[threadIdx.x] += t;
        __syncthreads();
    }
    if (threadIdx.x < nb) bsum[threadIdx.x] = buf[threadIdx.x];
}

__global__ void k_scan3(int* __restrict__ row_ptr, const int* __restrict__ bsum) {
    int i = blockIdx.x * 256 + threadIdx.x;
    if (i > Nn) return;
    if (i == 0) { row_ptr[0] = 0; return; }
    int b = (i - 1) >> 8;
    if (b > 0) row_ptr[i] += bsum[b - 1];
}

__global__ void k_scatter(const int* __restrict__ ei, int* __restrict__ cursor,
                          int* __restrict__ src_perm, int* __restrict__ eperm) {
    int e = blockIdx.x * blockDim.x + threadIdx.x;
    if (e >= Ee) return;
    int dst = ei[Ee + e];
    int pos = atomicAdd(&cursor[dst], 1);
    src_perm[pos] = ei[e];
    eperm[pos] = e;
}

__global__ void k_easort(const float* __restrict__ ea, const int* __restrict__ eperm,
                         __half* __restrict__ ea_h) {
    long t = (long)blockIdx.x * blockDim.x + threadIdx.x;
    if (t >= (long)Ee * 4) return;
    long idx = t >> 2;
    int e = eperm[idx];
    float4 v = ((const float4*)ea)[(long)e * 4 + (t & 3)];
    __half2 lo = __floats2half2_rn(v.x, v.y);
    __half2 hi = __floats2half2_rn(v.z, v.w);
    ((__half2*)ea_h)[t * 2]     = lo;
    ((__half2*)ea_h)[t * 2 + 1] = hi;
}

// ---------------- zero-global-atomic CSR build (main path) ----------------
// Device atomics retire at ~12 G/s on MI355X (R0/R2: 1.6M atomics == ~134us
// regardless of store count). So: NO per-edge global atomics anywhere.
// R8 lesson: NEVER put the latency-bound random ea gather in a 196-block
// kernel (8% occupancy -> 168us). Gather stays in the 6250-block scatB2.

__global__ __launch_bounds__(256) void k_cnt(const int* __restrict__ ei,
                                             int* __restrict__ table) {
    __shared__ int hist[NBK];
    for (int i = threadIdx.x; i < NBK; i += 256) hist[i] = 0;
    __syncthreads();
    int e0 = blockIdx.x * TB;
    for (int i = threadIdx.x; i < TB; i += 256) {
        int e = e0 + i;
        if (e >= Ee) break;
        atomicAdd(&hist[ei[Ee + e] >> 8], 1);    // LDS atomic
    }
    __syncthreads();
    for (int i = threadIdx.x; i < NBK; i += 256)
        table[i * NTB + blockIdx.x] = hist[i];   // column-major for per-bucket scan
}

__global__ __launch_bounds__(256) void k_colscan(int* __restrict__ table,
                                                 int* __restrict__ bktsz) {
    __shared__ int buf[1024];                    // NTB=782 <= 1024
    int c = blockIdx.x;
    for (int k = 0; k < 4; ++k) {
        int i = threadIdx.x + k * 256;
        buf[i] = (i < NTB) ? table[c * NTB + i] : 0;
    }
    __syncthreads();
    for (int off = 1; off < 1024; off <<= 1) {   // Hillis-Steele inclusive
        int v[4];
        for (int k = 0; k < 4; ++k) {
            int i = threadIdx.x + k * 256;
            v[k] = (i >= off) ? buf[i - off] : 0;
        }
        __syncthreads();
        for (int k = 0; k < 4; ++k) buf[threadIdx.x + k * 256] += v[k];
        __syncthreads();
    }
    for (int k = 0; k < 4; ++k) {
        int i = threadIdx.x + k * 256;
        if (i < NTB) table[c * NTB + i] = i ? buf[i - 1] : 0;  // exclusive
    }
    if (threadIdx.x == 0) bktsz[c] = buf[1023];
}

__global__ __launch_bounds__(256) void k_bktscan(const int* __restrict__ bktsz,
                                                 int* __restrict__ bktbase) {
    __shared__ int buf[256];
    int i = threadIdx.x;
    buf[i] = (i < NBK) ? bktsz[i] : 0;
    __syncthreads();
    for (int off = 1; off < 256; off <<= 1) {
        int v = (i >= off) ? buf[i - off] : 0;
        __syncthreads();
        buf[i] += v;
        __syncthreads();
    }
    if (i == 0) bktbase[0] = 0;
    if (i < NBK) bktbase[i + 1] = buf[i];
}

__global__ __launch_bounds__(256) void k_binfill(const int* __restrict__ ei,
                        const int* __restrict__ table, const int* __restrict__ bktbase,
                        unsigned long long* __restrict__ tmp) {
    __shared__ int off_s[NBK];
    __shared__ int cnt_s[NBK];
    for (int i = threadIdx.x; i < NBK; i += 256) {
        off_s[i] = table[i * NTB + blockIdx.x];
        cnt_s[i] = 0;
    }
    __syncthreads();
    int e0 = blockIdx.x * TB;
    for (int i = threadIdx.x; i < TB; i += 256) {
        int e = e0 + i;
        if (e >= Ee) break;
        int src = ei[e];
        int dst = ei[Ee + e];
        int b = dst >> 8;
        int r = atomicAdd(&cnt_s[b], 1);         // LDS atomic
        long pos = (long)bktbase[b] + off_s[b] + r;
        tmp[pos] = ((unsigned long long)(unsigned)dst << 37)
                 | ((unsigned long long)(unsigned)src << 21)
                 | (unsigned long long)(unsigned)e;
    }
}

// one block per bucket: LDS node-counts -> row_ptr, then place src/eord at
// final CSR positions (cheap 4B stores in the bucket's L2 span). R6 form.
__global__ __launch_bounds__(256) void k_bktB(const unsigned long long* __restrict__ tmp,
                        const int* __restrict__ bktbase, int* __restrict__ row_ptr,
                        int* __restrict__ src_perm, int* __restrict__ eord) {
    __shared__ int cnt[256];
    __shared__ int sc[256];
    __shared__ int lro[256];
    int b = blockIdx.x, tid = threadIdx.x;
    cnt[tid] = 0;
    __syncthreads();
    int s = bktbase[b], t_end = bktbase[b + 1];
    for (int i = s + tid; i < t_end; i += 256)
        atomicAdd(&cnt[(int)(tmp[i] >> 37) & 255], 1);
    __syncthreads();
    sc[tid] = cnt[tid];
    __syncthreads();
    for (int off = 1; off < 256; off <<= 1) {
        int v = (tid >= off) ? sc[tid - off] : 0;
        __syncthreads();
        sc[tid] += v;
        __syncthreads();
    }
    lro[tid] = tid ? sc[tid - 1] : 0;            // exclusive local row offset
    cnt[tid] = 0;
    int n = b * 256 + tid;
    if (n < Nn) row_ptr[n] = s + lro[tid];
    if (b == NBK - 1 && tid == 0) row_ptr[Nn] = Ee;
    __syncthreads();
    for (int i = s + tid; i < t_end; i += 256) {
        unsigned long long p = tmp[i];
        int dn = (int)(p >> 37) & 255;
        int r = atomicAdd(&cnt[dn], 1);          // LDS atomic
        int pos = s + lro[dn] + r;
        src_perm[pos] = (int)((p >> 21) & 0xFFFFull);
        eord[pos] = (int)(p & 0x1FFFFFull);
    }
}

// 6250 blocks: coalesced eord read -> random ea row gather (NT: truly
// single-use) -> fully coalesced fp16 ea_h write.
__global__ void k_scatB2(const int* __restrict__ eord,
                         const float* __restrict__ ea, __half* __restrict__ ea_h) {
    int t = blockIdx.x * blockDim.x + threadIdx.x;
    if (t >= Ee) return;
    int e = eord[t];
    const f32x4v* er = (const f32x4v*)(ea + (size_t)e * 16);
    f32x4v v0 = __builtin_nontemporal_load(er);
    f32x4v v1 = __builtin_nontemporal_load(er + 1);
    f32x4v v2 = __builtin_nontemporal_load(er + 2);
    f32x4v v3 = __builtin_nontemporal_load(er + 3);
    __half2 h0 = __floats2half2_rn(v0[0], v0[1]), h1 = __floats2half2_rn(v0[2], v0[3]);
    __half2 h2 = __floats2half2_rn(v1[0], v1[1]), h3 = __floats2half2_rn(v1[2], v1[3]);
    __half2 h4 = __floats2half2_rn(v2[0], v2[1]), h5 = __floats2half2_rn(v2[2], v2[3]);
    __half2 h6 = __floats2half2_rn(v3[0], v3[1]), h7 = __floats2half2_rn(v3[2], v3[3]);
    uint4 a = make_uint4(*(unsigned*)&h0, *(unsigned*)&h1,
                         *(unsigned*)&h2, *(unsigned*)&h3);
    uint4 bb = make_uint4(*(unsigned*)&h4, *(unsigned*)&h5,
                          *(unsigned*)&h6, *(unsigned*)&h7);
    uint4* o = (uint4*)(ea_h + (size_t)t * 16);
    o[0] = a;
    o[1] = bb;
}

__global__ void k_gbound(const int* __restrict__ batch, int* __restrict__ gstart) {
    int n = blockIdx.x * blockDim.x + threadIdx.x;
    if (n >= Nn) return;
    int b = batch[n];
    if (n == 0) { for (int g = 0; g <= b; ++g) gstart[g] = 0; }
    else { int bp = batch[n - 1]; for (int g = bp + 1; g <= b; ++g) gstart[g] = n; }
    if (n == Nn - 1) { for (int g = b + 1; g <= Gg; ++g) gstart[g] = Nn; }
}

// ---------------- node kernels ----------------
__global__ __launch_bounds__(256) void k_encode(const float* __restrict__ x,
                         const float* __restrict__ Wn,
                         const float* __restrict__ bn, float* __restrict__ h) {
    __shared__ float sx[64 * 32];
    int base = blockIdx.x * 64;
    for (int i = threadIdx.x; i < 512; i += 256) {
        int off = i * 4, row = off >> 5;
        float4 v = (base + row < Nn) ? ((const float4*)(x))[(base * 32 + off) >> 2]
                                     : make_float4(0.f, 0.f, 0.f, 0.f);
        ((float4*)sx)[i] = v;
    }
    __syncthreads();
    int lane = threadIdx.x & 63, wv = threadIdx.x >> 6;
    float acc[16];
    float b = bn[lane];
#pragma unroll
    for (int nn = 0; nn < 16; ++nn) acc[nn] = b;
#pragma unroll 1
    for (int k0 = 0; k0 < 32; k0 += 4) {
        float w0 = Wn[(k0 + 0) * 64 + lane];
        float w1 = Wn[(k0 + 1) * 64 + lane];
        float w2 = Wn[(k0 + 2) * 64 + lane];
        float w3 = Wn[(k0 + 3) * 64 + lane];
#pragma unroll
        for (int nn = 0; nn < 16; ++nn) {
            int row = wv * 16 + nn;
            float4 hv = *(const float4*)&sx[row * 32 + k0];
            acc[nn] = fmaf(hv.x, w0, fmaf(hv.y, w1, fmaf(hv.z, w2, fmaf(hv.w, w3, acc[nn]))));
        }
    }
#pragma unroll
    for (int nn = 0; nn < 16; ++nn) {
        int n = base + wv * 16 + nn;
        if (n < Nn) h[(size_t)n * 64 + lane] = fmaxf(acc[nn], 0.f);
    }
}

// All 3 layers' Wqm/bqm (fp32) in one launch (block = layer).
__global__ void k_wqm3(const float* __restrict__ Wq_all, const float* __restrict__ bq_all,
                       const float* __restrict__ We_all, float* __restrict__ Wqm3,
                       float* __restrict__ bqm3) {
    int l = blockIdx.x;
    const float* Wq = Wq_all + l * 4096;
    const float* bq = bq_all + l * 64;
    const float* We = We_all + l * 1024;
    float* Wqm = Wqm3 + l * 4096;
    float* bqm = bqm3 + l * 64;
    for (int o = threadIdx.x; o < 64 * 64; o += 256) {
        int j = o >> 6, lp = o & 63, hh = lp >> 4, ii = lp & 15;
        float acc = 0.f;
#pragma unroll
        for (int c = 0; c < 16; ++c)
            acc += Wq[j * 64 + hh * 16 + c] * We[ii * 64 + hh * 16 + c];
        Wqm[o] = acc;
    }
    if (threadIdx.x < 64) {
        int hh = threadIdx.x >> 4, ii = threadIdx.x & 15;
        float acc = 0.f;
#pragma unroll
        for (int c = 0; c < 16; ++c)
            acc += bq[hh * 16 + c] * We[ii * 64 + hh * 16 + c];
        bqm[threadIdx.x] = acc;
    }
}

// Pack fp16 pair-interleaved weights: P[(k>>1)*128 + 2*col + (k&1)] = W[k][col].
// SC*log2e folded into Wq and Wqm. grid = 3 layers x 5 mats.
__global__ void k_pack(const float* __restrict__ Wq, const float* __restrict__ Wk,
                       const float* __restrict__ Wv, const float* __restrict__ Wqm3,
                       const float* __restrict__ Ws, __half* __restrict__ pw) {
    int l = blockIdx.x / 5, m = blockIdx.x % 5;
    const float SC = 0.25f * 1.4426950408889634f;  // 1/sqrt(C) * log2(e)
    const float* src;
    float sc = 1.f;
    if (m == 0)      { src = Wq + l * 4096;   sc = SC; }
    else if (m == 1) { src = Wk + l * 4096; }
    else if (m == 2) { src = Wv + l * 4096; }
    else if (m == 3) { src = Wqm3 + l * 4096; sc = SC; }
    else             { src = Ws + l * 4096; }
    __half* dst = pw + ((size_t)l * 5 + m) * 4096;
    for (int i = threadIdx.x; i < 4096; i += 256) {
        int k = i >> 6, c = i & 63;
        dst[(k >> 1) * 128 + 2 * c + (k & 1)] = __float2half_rn(src[i] * sc);
    }
}

// fdot2 5-in-1 GEMM: h staged fp16 in LDS, weights from packed fp16 pairs,
// v_dot2_f32_f16 accumulate. q,t stored fp16 (SC pre-folded).
// kv now stored INTERLEAVED: kvi[n][8g..8g+3]=k[4g..4g+3], [8g+4..8g+7]=
// v[4g..4g+3] -> edge pass reads k+v with ONE 16B load per src per lane.
__global__ __launch_bounds__(256) void k_qkvt2(const float* __restrict__ h,
                       const __half* __restrict__ pw,
                       const float* __restrict__ bq, const float* __restrict__ bk,
                       const float* __restrict__ bv, const float* __restrict__ bqm,
                       const float* __restrict__ bs,
                       __half* __restrict__ qn16, __half* __restrict__ kvi,
                       __half* __restrict__ tq16, float* __restrict__ sn) {
    __shared__ __half sh[64 * 64];
    int base = blockIdx.x * 64;
    for (int i = threadIdx.x; i < 1024; i += 256) {
        int off = i * 4, row = off >> 6;
        float4 v = (base + row < Nn) ? ((const float4*)(h))[((size_t)base * 64 + off) >> 2]
                                     : make_float4(0.f, 0.f, 0.f, 0.f);
        ((__half2*)sh)[i * 2]     = __floats2half2_rn(v.x, v.y);
        ((__half2*)sh)[i * 2 + 1] = __floats2half2_rn(v.z, v.w);
    }
    __syncthreads();
    int lane = threadIdx.x & 63, wv = threadIdx.x >> 6;
    const float SC = 0.25f * 1.4426950408889634f;
    const __half* Pq = pw;
    const __half* Pk = pw + 4096;
    const __half* Pv = pw + 8192;
    const __half* Pt = pw + 12288;
    const __half* Ps = pw + 16384;
    float aq[16], ak[16], av[16], at[16], as_[16];
    float _bq = bq[lane] * SC, _bk = bk[lane], _bv = bv[lane],
          _bt = bqm[lane] * SC, _bs = bs[lane];
#pragma unroll
    for (int nn = 0; nn < 16; ++nn) {
        aq[nn] = _bq; ak[nn] = _bk; av[nn] = _bv; at[nn] = _bt; as_[nn] = _bs;
    }
#pragma unroll 1
    for (int k0 = 0; k0 < 64; k0 += 4) {
        int pi = (k0 >> 1) * 128 + 2 * lane;
        f16x2 wq0 = *(const f16x2*)(Pq + pi), wq1 = *(const f16x2*)(Pq + pi + 128);
        f16x2 wk0 = *(const f16x2*)(Pk + pi), wk1 = *(const f16x2*)(Pk + pi + 128);
        f16x2 wv0 = *(const f16x2*)(Pv + pi), wv1 = *(const f16x2*)(Pv + pi + 128);
        f16x2 wt0 = *(const f16x2*)(Pt + pi), wt1 = *(const f16x2*)(Pt + pi + 128);
        f16x2 ws0 = *(const f16x2*)(Ps + pi), ws1 = *(const f16x2*)(Ps + pi + 128);
#pragma unroll
        for (int nn = 0; nn < 16; ++nn) {
            int row = wv * 16 + nn;
            f16x4 hv = *(const f16x4*)&sh[row * 64 + k0];
            f16x2 h01 = __builtin_shufflevector(hv, hv, 0, 1);
            f16x2 h23 = __builtin_shufflevector(hv, hv, 2, 3);
            aq[nn]  = fdot2f(h01, wq0, fdot2f(h23, wq1, aq[nn]));
            ak[nn]  = fdot2f(h01, wk0, fdot2f(h23, wk1, ak[nn]));
            av[nn]  = fdot2f(h01, wv0, fdot2f(h23, wv1, av[nn]));
            at[nn]  = fdot2f(h01, wt0, fdot2f(h23, wt1, at[nn]));
            as_[nn] = fdot2f(h01, ws0, fdot2f(h23, ws1, as_[nn]));
        }
    }
    int ko = 8 * (lane >> 2) + (lane & 3);       // interleaved k position
#pragma unroll
    for (int nn = 0; nn < 16; ++nn) {
        int n = base + wv * 16 + nn;
        if (n < Nn) {
            size_t o = (size_t)n * 64 + lane;
            qn16[o] = __float2half_rn(aq[nn]);
            tq16[o] = __float2half_rn(at[nn]);
            sn[o] = as_[nn];
            kvi[(size_t)n * 128 + ko]     = __float2half_rn(ak[nn]);
            kvi[(size_t)n * 128 + ko + 4] = __float2half_rn(av[nn]);
        }
    }
}

// ---- edge pass v8: R6 structure + interleaved kv (1x16B load per src) ----
// R5-R7: ~75us floor at FETCH~205MB, pinned by gather request service.
// kv interleave cuts VMEM gathers per 8-edge iter from 8 to 6 and kv sector
// touches per src from 2 to 1. Plain loads everywhere (R8 lesson: eah and
// src_perm are REUSED across the 3 layers -> NT threw away L2/L3 reuse).
__global__ __launch_bounds__(256) void k_layer8(float* __restrict__ h,
                      const __half* __restrict__ qn16, const __half* __restrict__ kvi,
                      const __half* __restrict__ tq16, const float* __restrict__ sn,
                      const int* __restrict__ row_ptr, const int* __restrict__ src_perm,
                      const __half* __restrict__ eah, const float* __restrict__ We) {
    __shared__ float sWe[1024];
    __shared__ float tE[4][64];
    __shared__ float tV[4][64];
    for (int t = threadIdx.x; t < 1024; t += 256) sWe[t] = We[t];
    __syncthreads();
    int lane = threadIdx.x & 63, wv = threadIdx.x >> 6;
    int slot = lane >> 4, sl = lane & 15;
    int hh = lane >> 4;
    const int xoff = 4 * (sl & 3);                 // within-head x offset
#pragma unroll 1
    for (int j = 0; j < 4; ++j) {
        int n = blockIdx.x * 16 + wv * 4 + j;
        if (n >= Nn) break;                        // wave-uniform
        int beg = row_ptr[n], end = row_ptr[n + 1];
        f16x4 qv = *(const f16x4*)(qn16 + (size_t)n * 64 + 4 * sl);
        f16x4 tv = *(const f16x4*)(tq16 + (size_t)n * 64 + 4 * sl);
        f16x2 qa = __builtin_shufflevector(qv, qv, 0, 1);
        f16x2 qb = __builtin_shufflevector(qv, qv, 2, 3);
        f16x2 ta = __builtin_shufflevector(tv, tv, 0, 1);
        f16x2 tb = __builtin_shufflevector(tv, tv, 2, 3);
        float accd = 0.f;
        float4 accv = make_float4(0.f, 0.f, 0.f, 0.f);
        float4 acce = make_float4(0.f, 0.f, 0.f, 0.f);
        for (int idx = beg; idx < end; idx += 8) {
            int e0 = idx + slot, e1 = idx + 4 + slot;
            bool ok0 = e0 < end, ok1 = e1 < end;
            int i0 = ok0 ? e0 : beg, i1 = ok1 ? e1 : beg;
            int s0 = src_perm[i0], s1 = src_perm[i1];
            f16x8 kv0 = *(const f16x8*)(kvi + (size_t)s0 * 128 + 8 * sl);
            f16x8 kv1 = *(const f16x8*)(kvi + (size_t)s1 * 128 + 8 * sl);
            f16x4 x0 = *(const f16x4*)(eah + (size_t)i0 * 16 + xoff);
            f16x4 x1 = *(const f16x4*)(eah + (size_t)i1 * 16 + xoff);
            // dot over this lane's 4 channels; init -6 => -24 after 4-lane reduce
            float a0 = fdot2f(qa, __builtin_shufflevector(kv0, kv0, 0, 1),
                       fdot2f(qb, __builtin_shufflevector(kv0, kv0, 2, 3),
                       fdot2f(ta, __builtin_shufflevector(x0, x0, 0, 1),
                       fdot2f(tb, __builtin_shufflevector(x0, x0, 2, 3), -6.0f))));
            float a1 = fdot2f(qa, __builtin_shufflevector(kv1, kv1, 0, 1),
                       fdot2f(qb, __builtin_shufflevector(kv1, kv1, 2, 3),
                       fdot2f(ta, __builtin_shufflevector(x1, x1, 0, 1),
                       fdot2f(tb, __builtin_shufflevector(x1, x1, 2, 3), -6.0f))));
            a0 += __shfl_xor(a0, 1, 4); a1 += __shfl_xor(a1, 1, 4);
            a0 += __shfl_xor(a0, 2, 4); a1 += __shfl_xor(a1, 2, 4);
            float p0 = ok0 ? __builtin_exp2f(a0) : 0.f;
            float p1 = ok1 ? __builtin_exp2f(a1) : 0.f;
            accd += p0 + p1;
            accv.x = fmaf(p0, (float)kv0[4], fmaf(p1, (float)kv1[4], accv.x));
            accv.y = fmaf(p0, (float)kv0[5], fmaf(p1, (float)kv1[5], accv.y));
            accv.z = fmaf(p0, (float)kv0[6], fmaf(p1, (float)kv1[6], accv.z));
            accv.w = fmaf(p0, (float)kv0[7], fmaf(p1, (float)kv1[7], accv.w));
            acce.x = fmaf(p0, (float)x0[0], fmaf(p1, (float)x1[0], acce.x));
            acce.y = fmaf(p0, (float)x0[1], fmaf(p1, (float)x1[1], acce.y));
            acce.z = fmaf(p0, (float)x0[2], fmaf(p1, (float)x1[2], acce.z));
            acce.w = fmaf(p0, (float)x0[3], fmaf(p1, (float)x1[3], acce.w));
        }
        // merge the 4 independent slots (shared fixed shift -> plain adds)
        accd   += __shfl_xor(accd, 16);   accd   += __shfl_xor(accd, 32);
        accv.x += __shfl_xor(accv.x, 16); accv.x += __shfl_xor(accv.x, 32);
        accv.y += __shfl_xor(accv.y, 16); accv.y += __shfl_xor(accv.y, 32);
        accv.z += __shfl_xor(accv.z, 16); accv.z += __shfl_xor(accv.z, 32);
        accv.w += __shfl_xor(accv.w, 16); accv.w += __shfl_xor(accv.w, 32);
        acce.x += __shfl_xor(acce.x, 16); acce.x += __shfl_xor(acce.x, 32);
        acce.y += __shfl_xor(acce.y, 16); acce.y += __shfl_xor(acce.y, 32);
        acce.z += __shfl_xor(acce.z, 16); acce.z += __shfl_xor(acce.z, 32);
        acce.w += __shfl_xor(acce.w, 16); acce.w += __shfl_xor(acce.w, 32);
        float inv = 1.f / (accd + 1e-16f);
        if (slot == 0) {
            ((float4*)tE[wv])[sl] = make_float4(acce.x * inv, acce.y * inv,
                                                acce.z * inv, acce.w * inv);
            ((float4*)tV[wv])[sl] = make_float4(accv.x * inv, accv.y * inv,
                                                accv.z * inv, accv.w * inv);
        }
        // wave-lockstep LDS round-trip (same wave wrote it; no barrier)
        float re = 0.f;
#pragma unroll
        for (int i = 0; i < 16; ++i)
            re = fmaf(tE[wv][hh * 16 + i], sWe[i * 64 + lane], re);
        size_t o = (size_t)n * 64 + lane;
        float hv = h[o];
        h[o] = hv + fmaxf(tV[wv][lane] + re + sn[o], 0.f);
    }
}

// legacy edge pass (fallback mode 0 only: fp32 ea gather via eperm).
// kv indexing updated for the interleaved layout.
__global__ __launch_bounds__(256) void k_layer(float* __restrict__ h,
                      const __half* __restrict__ qn16, const __half* __restrict__ kvi,
                      const __half* __restrict__ tq16, const float* __restrict__ sn,
                      const int* __restrict__ row_ptr, const int* __restrict__ src_perm,
                      const int* __restrict__ eperm, const float* __restrict__ eaf,
                      const float* __restrict__ We) {
    __shared__ float sWe[1024];
    __shared__ float tile[4][64];
    for (int t = threadIdx.x; t < 1024; t += 256) sWe[t] = We[t];
    __syncthreads();
    int lane = threadIdx.x & 63, wv = threadIdx.x >> 6;
    int hh = lane >> 4, cc = lane & 15;
    int ko = 8 * (lane >> 2) + (lane & 3);
    int n = blockIdx.x * 4 + wv;
    if (n >= Nn) return;
    int beg = row_ptr[n], end = row_ptr[n + 1];
    float q = __half2float(qn16[(size_t)n * 64 + lane]);
    float t = __half2float(tq16[(size_t)n * 64 + lane]);
    float m = -INFINITY, accd = 0.f, accv = 0.f, acce = 0.f;
    int idx = beg;
    for (; idx < end; ++idx) {
        long b0 = (long)src_perm[idx] * 128;
        float k0 = __half2float(kvi[b0 + ko]);
        float v0 = __half2float(kvi[b0 + ko + 4]);
        float x0 = eaf[(long)eperm[idx] * 16 + cc];
        float a0 = fmaf(q, k0, x0 * t);
        a0 += __shfl_xor(a0, 1, 16);
        a0 += __shfl_xor(a0, 2, 16);
        a0 += __shfl_xor(a0, 4, 16);
        a0 += __shfl_xor(a0, 8, 16);
        float nm = fmaxf(m, a0);
        float w = __builtin_exp2f(m - nm);
        float p0 = __builtin_exp2f(a0 - nm);
        accd = fmaf(accd, w, p0);
        accv = fmaf(accv, w, p0 * v0);
        acce = fmaf(acce, w, p0 * x0);
        m = nm;
    }
    float inv = 1.f / (accd + 1e-16f);
    tile[wv][lane] = acce * inv;
    float re = 0.f;
#pragma unroll
    for (int i = 0; i < 16; ++i)
        re = fmaf(tile[wv][hh * 16 + i], sWe[i * 64 + lane], re);
    size_t o = (size_t)n * 64 + lane;
    float hv = h[o];
    h[o] = hv + fmaxf(fmaf(accv, inv, re + sn[o]), 0.f);
}

__global__ void k_pool(const float* __restrict__ h, const int* __restrict__ gstart,
                       const float* __restrict__ W1, const float* __restrict__ b1,
                       const float* __restrict__ W2, const float* __restrict__ b2,
                       float* __restrict__ out) {
    int g = blockIdx.x;
    int lane = threadIdx.x & 63, wv = threadIdx.x >> 6;
    int beg = gstart[g], end = gstart[g + 1];
    __shared__ float red[4][64];
    __shared__ float sp[64];
    __shared__ float sh[32];
    float acc = 0.f;
    for (int n = beg + wv; n < end; n += 4) acc += h[(size_t)n * 64 + lane];
    red[wv][lane] = acc;
    __syncthreads();
    if (threadIdx.x < 64) {
        float c = fmaxf((float)(end - beg), 1.f);
        sp[lane] = (red[0][lane] + red[1][lane] + red[2][lane] + red[3][lane]) / c;
    }
    __syncthreads();
    if (threadIdx.x < 32) {
        int t = threadIdx.x;
        float a = b1[t];
#pragma unroll
        for (int i = 0; i < 64; ++i) a = fmaf(sp[i], W1[i * 32 + t], a);
        sh[t] = fmaxf(a, 0.f) * W2[t];
    }
    __syncthreads();
    if (threadIdx.x == 0) {
        float s = b2[0];
#pragma unroll
        for (int i = 0; i < 32; ++i) s += sh[i];
        out[g] = s;
    }
}

extern "C" void kernel_launch(void* const* d_in, const int* in_sizes, int n_in,
                              void* d_out, int out_size, void* d_ws, size_t ws_size,
                              hipStream_t stream) {
    const float* x   = (const float*)d_in[0];
    const int*   ei  = (const int*)d_in[1];
    const float* ea  = (const float*)d_in[2];
    const int*   bat = (const int*)d_in[3];
    const float* Wn  = (const float*)d_in[4];
    const float* bn  = (const float*)d_in[5];
    const float* Wq  = (const float*)d_in[6];
    const float* bq  = (const float*)d_in[7];
    const float* Wk  = (const float*)d_in[8];
    const float* bk  = (const float*)d_in[9];
    const float* Wv  = (const float*)d_in[10];
    const float* bv  = (const float*)d_in[11];
    const float* We  = (const float*)d_in[12];
    const float* Wsk = (const float*)d_in[13];
    const float* bs  = (const float*)d_in[14];
    const float* W1  = (const float*)d_in[15];
    const float* b1  = (const float*)d_in[16];
    const float* W2  = (const float*)d_in[17];
    const float* b2  = (const float*)d_in[18];
    float* out = (float*)d_out;

    const size_t NH = (size_t)Nn * 64;
    float* h    = (float*)d_ws;
    float* qn   = h + NH;                      // fp16 q (uses half the slot)
    float* tq   = h + 2 * NH;                  // fp16 t
    float* sn   = h + 3 * NH;
    __half* kv  = (__half*)(h + 4 * NH);       // N*128 half == NH floats of space
    float* Wqm3 = h + 5 * NH;                  // 3*4096
    float* bqm3 = Wqm3 + 3 * 4096;             // 3*64
    __half* pw  = (__half*)(bqm3 + 3 * 64);    // 3*5*4096 packed fp16 weights
    int* deg       = (int*)(pw + 3 * 5 * 4096);   // N (legacy)
    int* row_ptr   = deg + Nn;                 // N+1
    int* cursor    = row_ptr + Nn + 1;         // N (legacy)
    int* src_perm  = cursor + Nn;              // E
    int* eperm     = src_perm + Ee;            // E (legacy fallback only)
    int* bsum      = eperm + Ee;               // 256 (legacy)
    int* gstart    = bsum + 256;               // G+1
    char* pe = (char*)(gstart + Gg + 1);
    __half* ea_h = (__half*)(((uintptr_t)pe + 63) & ~(uintptr_t)63);   // E*16 half
    char* pt = (char*)(ea_h + (size_t)Ee * 16);
    unsigned long long* tmp =
        (unsigned long long*)(((uintptr_t)pt + 15) & ~(uintptr_t)15);  // E u64
    size_t need_eah = ((char*)(ea_h + (size_t)Ee * 16)) - (char*)d_ws;
    size_t need_tmp = ((char*)(tmp + Ee)) - (char*)d_ws;
    // CSR-build scratch overlaid on qn/tq/sn (dead until k_qkvt2, and the
    // CSR build fully completes before k_qkvt2 in stream order):
    int* eord    = (int*)qn;                             // E ints
    int* table   = (int*)tq;                             // NBK*NTB ints (~613 KB)
    int* bktsz   = (int*)sn;                             // NBK
    int* bktbase = bktsz + 256;                          // NBK+1
    __half* qn16 = (__half*)qn;
    __half* tq16 = (__half*)tq;
    // mode 2: zero-global-atomic counting-sort CSR build (fast).
    // mode 1: legacy scatter + easort. mode 0: legacy scatter, fp32 ea gather.
    int mode = (ws_size >= need_tmp) ? 2 : (ws_size >= need_eah) ? 1 : 0;

    if (mode == 2) {
        k_cnt<<<NTB, 256, 0, stream>>>(ei, table);
        k_colscan<<<NBK, 256, 0, stream>>>(table, bktsz);
        k_bktscan<<<1, 256, 0, stream>>>(bktsz, bktbase);
        k_binfill<<<NTB, 256, 0, stream>>>(ei, table, bktbase, tmp);
        k_bktB<<<NBK, 256, 0, stream>>>(tmp, bktbase, row_ptr, src_perm, eord);
        k_scatB2<<<(Ee + 255) / 256, 256, 0, stream>>>(eord, ea, ea_h);
    } else {
        const int NB = 196;  // ceil(50000/256)
        hipMemsetAsync(deg, 0, Nn * sizeof(int), stream);
        k_hist<<<(Ee + 255) / 256, 256, 0, stream>>>(ei, deg);
        k_scan1<<<NB, 256, 0, stream>>>(deg, row_ptr, bsum);
        k_scan2<<<1, 256, 0, stream>>>(bsum, NB);
        k_scan3<<<(Nn + 256) / 256, 256, 0, stream>>>(row_ptr, bsum);
        hipMemcpyAsync(cursor, row_ptr, Nn * sizeof(int), hipMemcpyDeviceToDevice, stream);
        k_scatter<<<(Ee + 255) / 256, 256, 0, stream>>>(ei, cursor, src_perm, eperm);
        if (mode == 1)
            k_easort<<<((long)Ee * 4 + 255) / 256, 256, 0, stream>>>(ea, eperm, ea_h);
    }
    k_gbound<<<(Nn + 255) / 256, 256, 0, stream>>>(bat, gstart);
    k_wqm3<<<3, 256, 0, stream>>>(Wq, bq, We, Wqm3, bqm3);
    k_pack<<<15, 256, 0, stream>>>(Wq, Wk, Wv, Wqm3, Wsk, pw);

    int nodeBlocks = (Nn + 63) / 64;
    k_encode<<<nodeBlocks, 256, 0, stream>>>(x, Wn, bn, h);
    for (int l = 0; l < 3; ++l) {
        k_qkvt2<<<nodeBlocks, 256, 0, stream>>>(h, pw + (size_t)l * 5 * 4096,
                                                bq + l * 64, bk + l * 64, bv + l * 64,
                                                bqm3 + l * 64, bs + l * 64,
                                                qn16, kv, tq16, sn);
        if (mode >= 1)
            k_layer8<<<(Nn + 15) / 16, 256, 0, stream>>>(h, qn16, kv, tq16, sn,
                    row_ptr, src_perm, ea_h, We + l * 1024);
        else
            k_layer<<<(Nn + 3) / 4, 256, 0, stream>>>(h, qn16, kv, tq16, sn,
                    row_ptr, src_perm, eperm, ea, We + l * 1024);
    }
    k_pool<<<Gg, 256, 0, stream>>>(h, gstart, W1, b1, W2, b2, out);
}

// Round 10
// 657.720 us; speedup vs baseline: 1.2473x; 1.0392x over previous
//
#include <hip/hip_runtime.h>
#include <hip/hip_fp16.h>
#include <stdint.h>

#define Nn 50000
#define Ee 1600000
#define Gg 64
#define TB 2048                       // edges per bin-tile
#define NTB ((Ee + TB - 1) / TB)      // 782
#define NBK ((Nn + 63) / 64)          // 782 buckets of 64 dst nodes (R10: finer
                                      // buckets -> k_bktB 196->782 blocks, 4x occ)
#define SB2B 3125                     // scatB2 blocks at 2 rows/thread (E/512)

typedef _Float16 f16x2 __attribute__((ext_vector_type(2)));
typedef _Float16 f16x4 __attribute__((ext_vector_type(4)));
typedef _Float16 f16x8 __attribute__((ext_vector_type(8)));

__device__ __forceinline__ float fdot2f(f16x2 a, f16x2 b, float c) {
#if __has_builtin(__builtin_amdgcn_fdot2)
    return __builtin_amdgcn_fdot2(a, b, c, false);
#else
    return fmaf((float)a[0], (float)b[0], fmaf((float)a[1], (float)b[1], c));
#endif
}

// ---------------- legacy CSR build (fallback modes only) ----------------
__global__ void k_hist(const int* __restrict__ ei, int* __restrict__ deg) {
    int e = blockIdx.x * blockDim.x + threadIdx.x;
    if (e < Ee) atomicAdd(&deg[ei[Ee + e]], 1);
}

__global__ void k_scan1(const int* __restrict__ deg, int* __restrict__ row_ptr,
                        int* __restrict__ bsum) {
    __shared__ int buf[256];
    int i = blockIdx.x * 256 + threadIdx.x;
    int v = (i < Nn) ? deg[i] : 0;
    buf[threadIdx.x] = v;
    __syncthreads();
    for (int off = 1; off < 256; off <<= 1) {
        int t = (threadIdx.x >= off) ? buf[threadIdx.x - off] : 0;
        __syncthreads();
        buf[threadIdx.x] += t;
        __syncthreads();
    }
    if (i < Nn) row_ptr[i + 1] = buf[threadIdx.x];
    if (threadIdx.x == 255) bsum[blockIdx.x] = buf[255];
}

__global__ void k_scan2(int* __restrict__ bsum, int nb) {
    __shared__ int buf[256];
    int v = (threadIdx.x < nb) ? bsum[threadIdx.x] : 0;
    buf[threadIdx.x] = v;
    __syncthreads();
    for (int off = 1; off < 256; off <<= 1) {
        int t = (threadIdx.x >= off) ? buf[threadIdx.x - off] : 0;
        __syncthreads();
        buf[threadIdx.x] += t;
        __syncthreads();
    }
    if (threadIdx.x < nb) bsum[threadIdx.x] = buf[threadIdx.x];
}

__global__ void k_scan3(int* __restrict__ row_ptr, const int* __restrict__ bsum) {
    int i = blockIdx.x * 256 + threadIdx.x;
    if (i > Nn) return;
    if (i == 0) { row_ptr[0] = 0; return; }
    int b = (i - 1) >> 8;
    if (b > 0) row_ptr[i] += bsum[b - 1];
}

__global__ void k_scatter(const int* __restrict__ ei, int* __restrict__ cursor,
                          int* __restrict__ src_perm, int* __restrict__ eperm) {
    int e = blockIdx.x * blockDim.x + threadIdx.x;
    if (e >= Ee) return;
    int dst = ei[Ee + e];
    int pos = atomicAdd(&cursor[dst], 1);
    src_perm[pos] = ei[e];
    eperm[pos] = e;
}

__global__ void k_easort(const float* __restrict__ ea, const int* __restrict__ eperm,
                         __half* __restrict__ ea_h) {
    long t = (long)blockIdx.x * blockDim.x + threadIdx.x;
    if (t >= (long)Ee * 4) return;
    long idx = t >> 2;
    int e = eperm[idx];
    float4 v = ((const float4*)ea)[(long)e * 4 + (t & 3)];
    __half2 lo = __floats2half2_rn(v.x, v.y);
    __half2 hi = __floats2half2_rn(v.z, v.w);
    ((__half2*)ea_h)[t * 2]     = lo;
    ((__half2*)ea_h)[t * 2 + 1] = hi;
}

// ---------------- zero-global-atomic CSR build (main path) ----------------
// Device atomics retire at ~12 G/s on MI355X (R0/R2: 1.6M atomics == ~134us).
// NO per-edge global atomics. R8 lesson: never run the random ea gather at
// 196-block occupancy. R9 lesson: no NT on data with any line-level reuse.

__global__ __launch_bounds__(256) void k_cnt(const int* __restrict__ ei,
                                             int* __restrict__ table) {
    __shared__ int hist[NBK];
    for (int i = threadIdx.x; i < NBK; i += 256) hist[i] = 0;
    __syncthreads();
    int e0 = blockIdx.x * TB;
    for (int i = threadIdx.x; i < TB; i += 256) {
        int e = e0 + i;
        if (e >= Ee) break;
        atomicAdd(&hist[ei[Ee + e] >> 6], 1);    // LDS atomic; bucket = 64 nodes
    }
    __syncthreads();
    for (int i = threadIdx.x; i < NBK; i += 256)
        table[i * NTB + blockIdx.x] = hist[i];   // column-major for per-bucket scan
}

__global__ __launch_bounds__(256) void k_colscan(int* __restrict__ table,
                                                 int* __restrict__ bktsz) {
    __shared__ int buf[1024];                    // NTB=782 <= 1024
    int c = blockIdx.x;
    for (int k = 0; k < 4; ++k) {
        int i = threadIdx.x + k * 256;
        buf[i] = (i < NTB) ? table[c * NTB + i] : 0;
    }
    __syncthreads();
    for (int off = 1; off < 1024; off <<= 1) {   // Hillis-Steele inclusive
        int v[4];
        for (int k = 0; k < 4; ++k) {
            int i = threadIdx.x + k * 256;
            v[k] = (i >= off) ? buf[i - off] : 0;
        }
        __syncthreads();
        for (int k = 0; k < 4; ++k) buf[threadIdx.x + k * 256] += v[k];
        __syncthreads();
    }
    for (int k = 0; k < 4; ++k) {
        int i = threadIdx.x + k * 256;
        if (i < NTB) table[c * NTB + i] = i ? buf[i - 1] : 0;  // exclusive
    }
    if (threadIdx.x == 0) bktsz[c] = buf[1023];
}

// exclusive scan of NBK=782 bucket sizes (1024-wide Hillis-Steele, 1 block)
__global__ __launch_bounds__(256) void k_bktscan(const int* __restrict__ bktsz,
                                                 int* __restrict__ bktbase) {
    __shared__ int buf[1024];
    for (int k = 0; k < 4; ++k) {
        int i = threadIdx.x + k * 256;
        buf[i] = (i < NBK) ? bktsz[i] : 0;
    }
    __syncthreads();
    for (int off = 1; off < 1024; off <<= 1) {
        int v[4];
        for (int k = 0; k < 4; ++k) {
            int i = threadIdx.x + k * 256;
            v[k] = (i >= off) ? buf[i - off] : 0;
        }
        __syncthreads();
        for (int k = 0; k < 4; ++k) buf[threadIdx.x + k * 256] += v[k];
        __syncthreads();
    }
    for (int k = 0; k < 4; ++k) {
        int i = threadIdx.x + k * 256;
        if (i < NBK) bktbase[i + 1] = buf[i];
    }
    if (threadIdx.x == 0) bktbase[0] = 0;
}

__global__ __launch_bounds__(256) void k_binfill(const int* __restrict__ ei,
                        const int* __restrict__ table, const int* __restrict__ bktbase,
                        unsigned long long* __restrict__ tmp) {
    __shared__ int off_s[NBK];
    __shared__ int cnt_s[NBK];
    for (int i = threadIdx.x; i < NBK; i += 256) {
        off_s[i] = table[i * NTB + blockIdx.x];
        cnt_s[i] = 0;
    }
    __syncthreads();
    int e0 = blockIdx.x * TB;
    for (int i = threadIdx.x; i < TB; i += 256) {
        int e = e0 + i;
        if (e >= Ee) break;
        int src = ei[e];
        int dst = ei[Ee + e];
        int b = dst >> 6;
        int r = atomicAdd(&cnt_s[b], 1);         // LDS atomic
        long pos = (long)bktbase[b] + off_s[b] + r;
        tmp[pos] = ((unsigned long long)(unsigned)dst << 37)
                 | ((unsigned long long)(unsigned)src << 21)
                 | (unsigned long long)(unsigned)e;
    }
}

// one block per 64-node bucket (782 blocks, 4x the old occupancy): LDS
// node-counts -> row_ptr, then place src/eord at final CSR positions
// (cheap 4B stores confined to the bucket's ~8KB L2-resident span).
__global__ __launch_bounds__(256) void k_bktB(const unsigned long long* __restrict__ tmp,
                        const int* __restrict__ bktbase, int* __restrict__ row_ptr,
                        int* __restrict__ src_perm, int* __restrict__ eord) {
    __shared__ int cnt[64];
    __shared__ int sc[64];
    __shared__ int lro[64];
    int b = blockIdx.x, tid = threadIdx.x;
    if (tid < 64) cnt[tid] = 0;
    __syncthreads();
    int s = bktbase[b], t_end = bktbase[b + 1];
    for (int i = s + tid; i < t_end; i += 256)
        atomicAdd(&cnt[(int)(tmp[i] >> 37) & 63], 1);
    __syncthreads();
    if (tid < 64) sc[tid] = cnt[tid];
    __syncthreads();
    for (int off = 1; off < 64; off <<= 1) {
        int v = (tid < 64 && tid >= off) ? sc[tid - off] : 0;
        __syncthreads();
        if (tid < 64) sc[tid] += v;
        __syncthreads();
    }
    if (tid < 64) {
        lro[tid] = tid ? sc[tid - 1] : 0;        // exclusive local row offset
        cnt[tid] = 0;
        int n = b * 64 + tid;
        if (n < Nn) row_ptr[n] = s + lro[tid];
    }
    if (b == NBK - 1 && tid == 0) row_ptr[Nn] = Ee;
    __syncthreads();
    for (int i = s + tid; i < t_end; i += 256) {
        unsigned long long p = tmp[i];
        int dn = (int)(p >> 37) & 63;
        int r = atomicAdd(&cnt[dn], 1);          // LDS atomic
        int pos = s + lro[dn] + r;
        src_perm[pos] = (int)((p >> 21) & 0xFFFFull);
        eord[pos] = (int)(p & 0x1FFFFFull);
    }
}

// scatB2 body: 2 rows/thread (8 independent 16B loads in flight), PLAIN
// loads (R9: NT on ea lost the partner-half 128B-line L2 hits, 81us).
__device__ __forceinline__ void scatB2_body(int bid, const int* __restrict__ eord,
                        const float* __restrict__ ea, __half* __restrict__ ea_h) {
    int t0 = (bid * 256 + threadIdx.x) * 2;
    if (t0 >= Ee) return;
    int e0 = eord[t0], e1 = eord[t0 + 1];        // Ee even -> t0+1 always valid
    const float4* r0 = (const float4*)(ea + (size_t)e0 * 16);
    const float4* r1 = (const float4*)(ea + (size_t)e1 * 16);
    float4 a0 = r0[0], a1 = r0[1], a2 = r0[2], a3 = r0[3];
    float4 c0 = r1[0], c1 = r1[1], c2 = r1[2], c3 = r1[3];
    __half2 h0 = __floats2half2_rn(a0.x, a0.y), h1 = __floats2half2_rn(a0.z, a0.w);
    __half2 h2 = __floats2half2_rn(a1.x, a1.y), h3 = __floats2half2_rn(a1.z, a1.w);
    __half2 h4 = __floats2half2_rn(a2.x, a2.y), h5 = __floats2half2_rn(a2.z, a2.w);
    __half2 h6 = __floats2half2_rn(a3.x, a3.y), h7 = __floats2half2_rn(a3.z, a3.w);
    __half2 g0 = __floats2half2_rn(c0.x, c0.y), g1 = __floats2half2_rn(c0.z, c0.w);
    __half2 g2 = __floats2half2_rn(c1.x, c1.y), g3 = __floats2half2_rn(c1.z, c1.w);
    __half2 g4 = __floats2half2_rn(c2.x, c2.y), g5 = __floats2half2_rn(c2.z, c2.w);
    __half2 g6 = __floats2half2_rn(c3.x, c3.y), g7 = __floats2half2_rn(c3.z, c3.w);
    uint4* o = (uint4*)(ea_h + (size_t)t0 * 16);
    o[0] = make_uint4(*(unsigned*)&h0, *(unsigned*)&h1, *(unsigned*)&h2, *(unsigned*)&h3);
    o[1] = make_uint4(*(unsigned*)&h4, *(unsigned*)&h5, *(unsigned*)&h6, *(unsigned*)&h7);
    o[2] = make_uint4(*(unsigned*)&g0, *(unsigned*)&g1, *(unsigned*)&g2, *(unsigned*)&g3);
    o[3] = make_uint4(*(unsigned*)&g4, *(unsigned*)&g5, *(unsigned*)&g6, *(unsigned*)&g7);
}

__global__ void k_scatB2(const int* __restrict__ eord,
                         const float* __restrict__ ea, __half* __restrict__ ea_h) {
    scatB2_body(blockIdx.x, eord, ea, ea_h);
}

__global__ void k_gbound(const int* __restrict__ batch, int* __restrict__ gstart) {
    int n = blockIdx.x * blockDim.x + threadIdx.x;
    if (n >= Nn) return;
    int b = batch[n];
    if (n == 0) { for (int g = 0; g <= b; ++g) gstart[g] = 0; }
    else { int bp = batch[n - 1]; for (int g = bp + 1; g <= b; ++g) gstart[g] = n; }
    if (n == Nn - 1) { for (int g = b + 1; g <= Gg; ++g) gstart[g] = Nn; }
}

// ---------------- node kernels ----------------
__global__ __launch_bounds__(256) void k_encode(const float* __restrict__ x,
                         const float* __restrict__ Wn,
                         const float* __restrict__ bn, float* __restrict__ h) {
    __shared__ float sx[64 * 32];
    int base = blockIdx.x * 64;
    for (int i = threadIdx.x; i < 512; i += 256) {
        int off = i * 4, row = off >> 5;
        float4 v = (base + row < Nn) ? ((const float4*)(x))[(base * 32 + off) >> 2]
                                     : make_float4(0.f, 0.f, 0.f, 0.f);
        ((float4*)sx)[i] = v;
    }
    __syncthreads();
    int lane = threadIdx.x & 63, wv = threadIdx.x >> 6;
    float acc[16];
    float b = bn[lane];
#pragma unroll
    for (int nn = 0; nn < 16; ++nn) acc[nn] = b;
#pragma unroll 1
    for (int k0 = 0; k0 < 32; k0 += 4) {
        float w0 = Wn[(k0 + 0) * 64 + lane];
        float w1 = Wn[(k0 + 1) * 64 + lane];
        float w2 = Wn[(k0 + 2) * 64 + lane];
        float w3 = Wn[(k0 + 3) * 64 + lane];
#pragma unroll
        for (int nn = 0; nn < 16; ++nn) {
            int row = wv * 16 + nn;
            float4 hv = *(const float4*)&sx[row * 32 + k0];
            acc[nn] = fmaf(hv.x, w0, fmaf(hv.y, w1, fmaf(hv.z, w2, fmaf(hv.w, w3, acc[nn]))));
        }
    }
#pragma unroll
    for (int nn = 0; nn < 16; ++nn) {
        int n = base + wv * 16 + nn;
        if (n < Nn) h[(size_t)n * 64 + lane] = fmaxf(acc[nn], 0.f);
    }
}

// All 3 layers' Wqm/bqm (fp32) in one launch (block = layer).
__global__ void k_wqm3(const float* __restrict__ Wq_all, const float* __restrict__ bq_all,
                       const float* __restrict__ We_all, float* __restrict__ Wqm3,
                       float* __restrict__ bqm3) {
    int l = blockIdx.x;
    const float* Wq = Wq_all + l * 4096;
    const float* bq = bq_all + l * 64;
    const float* We = We_all + l * 1024;
    float* Wqm = Wqm3 + l * 4096;
    float* bqm = bqm3 + l * 64;
    for (int o = threadIdx.x; o < 64 * 64; o += 256) {
        int j = o >> 6, lp = o & 63, hh = lp >> 4, ii = lp & 15;
        float acc = 0.f;
#pragma unroll
        for (int c = 0; c < 16; ++c)
            acc += Wq[j * 64 + hh * 16 + c] * We[ii * 64 + hh * 16 + c];
        Wqm[o] = acc;
    }
    if (threadIdx.x < 64) {
        int hh = threadIdx.x >> 4, ii = threadIdx.x & 15;
        float acc = 0.f;
#pragma unroll
        for (int c = 0; c < 16; ++c)
            acc += bq[hh * 16 + c] * We[ii * 64 + hh * 16 + c];
        bqm[threadIdx.x] = acc;
    }
}

// Pack fp16 pair-interleaved weights: P[(k>>1)*128 + 2*col + (k&1)] = W[k][col].
// SC*log2e folded into Wq and Wqm. grid = 3 layers x 5 mats.
__global__ void k_pack(const float* __restrict__ Wq, const float* __restrict__ Wk,
                       const float* __restrict__ Wv, const float* __restrict__ Wqm3,
                       const float* __restrict__ Ws, __half* __restrict__ pw) {
    int l = blockIdx.x / 5, m = blockIdx.x % 5;
    const float SC = 0.25f * 1.4426950408889634f;  // 1/sqrt(C) * log2(e)
    const float* src;
    float sc = 1.f;
    if (m == 0)      { src = Wq + l * 4096;   sc = SC; }
    else if (m == 1) { src = Wk + l * 4096; }
    else if (m == 2) { src = Wv + l * 4096; }
    else if (m == 3) { src = Wqm3 + l * 4096; sc = SC; }
    else             { src = Ws + l * 4096; }
    __half* dst = pw + ((size_t)l * 5 + m) * 4096;
    for (int i = threadIdx.x; i < 4096; i += 256) {
        int k = i >> 6, c = i & 63;
        dst[(k >> 1) * 128 + 2 * c + (k & 1)] = __float2half_rn(src[i] * sc);
    }
}

// fdot2 5-in-1 GEMM body: h staged fp16 in LDS, packed fp16 weights,
// v_dot2_f32_f16 accumulate. q,t stored fp16 (SC pre-folded). kv stored
// interleaved: kvi[n][8g..8g+3]=k[4g..], [8g+4..8g+7]=v[4g..].
__device__ __forceinline__ void qkvt2_body(int bid, const float* __restrict__ h,
                       const __half* __restrict__ pw,
                       const float* __restrict__ bq, const float* __restrict__ bk,
                       const float* __restrict__ bv, const float* __restrict__ bqm,
                       const float* __restrict__ bs,
                       __half* __restrict__ qn16, __half* __restrict__ kvi,
                       __half* __restrict__ tq16, float* __restrict__ sn) {
    __shared__ __half sh[64 * 64];
    int base = bid * 64;
    for (int i = threadIdx.x; i < 1024; i += 256) {
        int off = i * 4, row = off >> 6;
        float4 v = (base + row < Nn) ? ((const float4*)(h))[((size_t)base * 64 + off) >> 2]
                                     : make_float4(0.f, 0.f, 0.f, 0.f);
        ((__half2*)sh)[i * 2]     = __floats2half2_rn(v.x, v.y);
        ((__half2*)sh)[i * 2 + 1] = __floats2half2_rn(v.z, v.w);
    }
    __syncthreads();
    int lane = threadIdx.x & 63, wv = threadIdx.x >> 6;
    const float SC = 0.25f * 1.4426950408889634f;
    const __half* Pq = pw;
    const __half* Pk = pw + 4096;
    const __half* Pv = pw + 8192;
    const __half* Pt = pw + 12288;
    const __half* Ps = pw + 16384;
    float aq[16], ak[16], av[16], at[16], as_[16];
    float _bq = bq[lane] * SC, _bk = bk[lane], _bv = bv[lane],
          _bt = bqm[lane] * SC, _bs = bs[lane];
#pragma unroll
    for (int nn = 0; nn < 16; ++nn) {
        aq[nn] = _bq; ak[nn] = _bk; av[nn] = _bv; at[nn] = _bt; as_[nn] = _bs;
    }
#pragma unroll 1
    for (int k0 = 0; k0 < 64; k0 += 4) {
        int pi = (k0 >> 1) * 128 + 2 * lane;
        f16x2 wq0 = *(const f16x2*)(Pq + pi), wq1 = *(const f16x2*)(Pq + pi + 128);
        f16x2 wk0 = *(const f16x2*)(Pk + pi), wk1 = *(const f16x2*)(Pk + pi + 128);
        f16x2 wv0 = *(const f16x2*)(Pv + pi), wv1 = *(const f16x2*)(Pv + pi + 128);
        f16x2 wt0 = *(const f16x2*)(Pt + pi), wt1 = *(const f16x2*)(Pt + pi + 128);
        f16x2 ws0 = *(const f16x2*)(Ps + pi), ws1 = *(const f16x2*)(Ps + pi + 128);
#pragma unroll
        for (int nn = 0; nn < 16; ++nn) {
            int row = wv * 16 + nn;
            f16x4 hv = *(const f16x4*)&sh[row * 64 + k0];
            f16x2 h01 = __builtin_shufflevector(hv, hv, 0, 1);
            f16x2 h23 = __builtin_shufflevector(hv, hv, 2, 3);
            aq[nn]  = fdot2f(h01, wq0, fdot2f(h23, wq1, aq[nn]));
            ak[nn]  = fdot2f(h01, wk0, fdot2f(h23, wk1, ak[nn]));
            av[nn]  = fdot2f(h01, wv0, fdot2f(h23, wv1, av[nn]));
            at[nn]  = fdot2f(h01, wt0, fdot2f(h23, wt1, at[nn]));
            as_[nn] = fdot2f(h01, ws0, fdot2f(h23, ws1, as_[nn]));
        }
    }
    int ko = 8 * (lane >> 2) + (lane & 3);       // interleaved k position
#pragma unroll
    for (int nn = 0; nn < 16; ++nn) {
        int n = base + wv * 16 + nn;
        if (n < Nn) {
            size_t o = (size_t)n * 64 + lane;
            qn16[o] = __float2half_rn(aq[nn]);
            tq16[o] = __float2half_rn(at[nn]);
            sn[o] = as_[nn];
            kvi[(size_t)n * 128 + ko]     = __float2half_rn(ak[nn]);
            kvi[(size_t)n * 128 + ko + 4] = __float2half_rn(av[nn]);
        }
    }
}

__global__ __launch_bounds__(256) void k_qkvt2(const float* __restrict__ h,
                       const __half* __restrict__ pw,
                       const float* __restrict__ bq, const float* __restrict__ bk,
                       const float* __restrict__ bv, const float* __restrict__ bqm,
                       const float* __restrict__ bs,
                       __half* __restrict__ qn16, __half* __restrict__ kvi,
                       __half* __restrict__ tq16, float* __restrict__ sn) {
    qkvt2_body(blockIdx.x, h, pw, bq, bk, bv, bqm, bs, qn16, kvi, tq16, sn);
}

// FUSED: scatB2 (edge chain, latency-bound) + qkvt2 layer-0 (node chain,
// compute-bound) are mutually independent -> one grid, overlap the gather
// under the GEMM. eord lives in the eperm slot (no aliasing with qn16).
__global__ __launch_bounds__(256) void k_sqk(const int* __restrict__ eord,
                       const float* __restrict__ ea, __half* __restrict__ ea_h,
                       const float* __restrict__ h, const __half* __restrict__ pw,
                       const float* __restrict__ bq, const float* __restrict__ bk,
                       const float* __restrict__ bv, const float* __restrict__ bqm,
                       const float* __restrict__ bs,
                       __half* __restrict__ qn16, __half* __restrict__ kvi,
                       __half* __restrict__ tq16, float* __restrict__ sn) {
    if (blockIdx.x < SB2B)
        scatB2_body(blockIdx.x, eord, ea, ea_h);
    else
        qkvt2_body(blockIdx.x - SB2B, h, pw, bq, bk, bv, bqm, bs,
                   qn16, kvi, tq16, sn);
}

// ---- edge pass v8 (R9 form): 8-edge, interleaved kv, plain loads ----
__global__ __launch_bounds__(256) void k_layer8(float* __restrict__ h,
                      const __half* __restrict__ qn16, const __half* __restrict__ kvi,
                      const __half* __restrict__ tq16, const float* __restrict__ sn,
                      const int* __restrict__ row_ptr, const int* __restrict__ src_perm,
                      const __half* __restrict__ eah, const float* __restrict__ We) {
    __shared__ float sWe[1024];
    __shared__ float tE[4][64];
    __shared__ float tV[4][64];
    for (int t = threadIdx.x; t < 1024; t += 256) sWe[t] = We[t];
    __syncthreads();
    int lane = threadIdx.x & 63, wv = threadIdx.x >> 6;
    int slot = lane >> 4, sl = lane & 15;
    int hh = lane >> 4;
    const int xoff = 4 * (sl & 3);                 // within-head x offset
#pragma unroll 1
    for (int j = 0; j < 4; ++j) {
        int n = blockIdx.x * 16 + wv * 4 + j;
        if (n >= Nn) break;                        // wave-uniform
        int beg = row_ptr[n], end = row_ptr[n + 1];
        f16x4 qv = *(const f16x4*)(qn16 + (size_t)n * 64 + 4 * sl);
        f16x4 tv = *(const f16x4*)(tq16 + (size_t)n * 64 + 4 * sl);
        f16x2 qa = __builtin_shufflevector(qv, qv, 0, 1);
        f16x2 qb = __builtin_shufflevector(qv, qv, 2, 3);
        f16x2 ta = __builtin_shufflevector(tv, tv, 0, 1);
        f16x2 tb = __builtin_shufflevector(tv, tv, 2, 3);
        float accd = 0.f;
        float4 accv = make_float4(0.f, 0.f, 0.f, 0.f);
        float4 acce = make_float4(0.f, 0.f, 0.f, 0.f);
        for (int idx = beg; idx < end; idx += 8) {
            int e0 = idx + slot, e1 = idx + 4 + slot;
            bool ok0 = e0 < end, ok1 = e1 < end;
            int i0 = ok0 ? e0 : beg, i1 = ok1 ? e1 : beg;
            int s0 = src_perm[i0], s1 = src_perm[i1];
            f16x8 kv0 = *(const f16x8*)(kvi + (size_t)s0 * 128 + 8 * sl);
            f16x8 kv1 = *(const f16x8*)(kvi + (size_t)s1 * 128 + 8 * sl);
            f16x4 x0 = *(const f16x4*)(eah + (size_t)i0 * 16 + xoff);
            f16x4 x1 = *(const f16x4*)(eah + (size_t)i1 * 16 + xoff);
            // dot over this lane's 4 channels; init -6 => -24 after 4-lane reduce
            float a0 = fdot2f(qa, __builtin_shufflevector(kv0, kv0, 0, 1),
                       fdot2f(qb, __builtin_shufflevector(kv0, kv0, 2, 3),
                       fdot2f(ta, __builtin_shufflevector(x0, x0, 0, 1),
                       fdot2f(tb, __builtin_shufflevector(x0, x0, 2, 3), -6.0f))));
            float a1 = fdot2f(qa, __builtin_shufflevector(kv1, kv1, 0, 1),
                       fdot2f(qb, __builtin_shufflevector(kv1, kv1, 2, 3),
                       fdot2f(ta, __builtin_shufflevector(x1, x1, 0, 1),
                       fdot2f(tb, __builtin_shufflevector(x1, x1, 2, 3), -6.0f))));
            a0 += __shfl_xor(a0, 1, 4); a1 += __shfl_xor(a1, 1, 4);
            a0 += __shfl_xor(a0, 2, 4); a1 += __shfl_xor(a1, 2, 4);
            float p0 = ok0 ? __builtin_exp2f(a0) : 0.f;
            float p1 = ok1 ? __builtin_exp2f(a1) : 0.f;
            accd += p0 + p1;
            accv.x = fmaf(p0, (float)kv0[4], fmaf(p1, (float)kv1[4], accv.x));
            accv.y = fmaf(p0, (float)kv0[5], fmaf(p1, (float)kv1[5], accv.y));
            accv.z = fmaf(p0, (float)kv0[6], fmaf(p1, (float)kv1[6], accv.z));
            accv.w = fmaf(p0, (float)kv0[7], fmaf(p1, (float)kv1[7], accv.w));
            acce.x = fmaf(p0, (float)x0[0], fmaf(p1, (float)x1[0], acce.x));
            acce.y = fmaf(p0, (float)x0[1], fmaf(p1, (float)x1[1], acce.y));
            acce.z = fmaf(p0, (float)x0[2], fmaf(p1, (float)x1[2], acce.z));
            acce.w = fmaf(p0, (float)x0[3], fmaf(p1, (float)x1[3], acce.w));
        }
        // merge the 4 independent slots (shared fixed shift -> plain adds)
        accd   += __shfl_xor(accd, 16);   accd   += __shfl_xor(accd, 32);
        accv.x += __shfl_xor(accv.x, 16); accv.x += __shfl_xor(accv.x, 32);
        accv.y += __shfl_xor(accv.y, 16); accv.y += __shfl_xor(accv.y, 32);
        accv.z += __shfl_xor(accv.z, 16); accv.z += __shfl_xor(accv.z, 32);
        accv.w += __shfl_xor(accv.w, 16); accv.w += __shfl_xor(accv.w, 32);
        acce.x += __shfl_xor(acce.x, 16); acce.x += __shfl_xor(acce.x, 32);
        acce.y += __shfl_xor(acce.y, 16); acce.y += __shfl_xor(acce.y, 32);
        acce.z += __shfl_xor(acce.z, 16); acce.z += __shfl_xor(acce.z, 32);
        acce.w += __shfl_xor(acce.w, 16); acce.w += __shfl_xor(acce.w, 32);
        float inv = 1.f / (accd + 1e-16f);
        if (slot == 0) {
            ((float4*)tE[wv])[sl] = make_float4(acce.x * inv, acce.y * inv,
                                                acce.z * inv, acce.w * inv);
            ((float4*)tV[wv])[sl] = make_float4(accv.x * inv, accv.y * inv,
                                                accv.z * inv, accv.w * inv);
        }
        // wave-lockstep LDS round-trip (same wave wrote it; no barrier)
        float re = 0.f;
#pragma unroll
        for (int i = 0; i < 16; ++i)
            re = fmaf(tE[wv][hh * 16 + i], sWe[i * 64 + lane], re);
        size_t o = (size_t)n * 64 + lane;
        float hv = h[o];
        h[o] = hv + fmaxf(tV[wv][lane] + re + sn[o], 0.f);
    }
}

// legacy edge pass (fallback mode 0 only: fp32 ea gather via eperm).
__global__ __launch_bounds__(256) void k_layer(float* __restrict__ h,
                      const __half* __restrict__ qn16, const __half* __restrict__ kvi,
                      const __half* __restrict__ tq16, const float* __restrict__ sn,
                      const int* __restrict__ row_ptr, const int* __restrict__ src_perm,
                      const int* __restrict__ eperm, const float* __restrict__ eaf,
                      const float* __restrict__ We) {
    __shared__ float sWe[1024];
    __shared__ float tile[4][64];
    for (int t = threadIdx.x; t < 1024; t += 256) sWe[t] = We[t];
    __syncthreads();
    int lane = threadIdx.x & 63, wv = threadIdx.x >> 6;
    int hh = lane >> 4, cc = lane & 15;
    int ko = 8 * (lane >> 2) + (lane & 3);
    int n = blockIdx.x * 4 + wv;
    if (n >= Nn) return;
    int beg = row_ptr[n], end = row_ptr[n + 1];
    float q = __half2float(qn16[(size_t)n * 64 + lane]);
    float t = __half2float(tq16[(size_t)n * 64 + lane]);
    float m = -INFINITY, accd = 0.f, accv = 0.f, acce = 0.f;
    int idx = beg;
    for (; idx < end; ++idx) {
        long b0 = (long)src_perm[idx] * 128;
        float k0 = __half2float(kvi[b0 + ko]);
        float v0 = __half2float(kvi[b0 + ko + 4]);
        float x0 = eaf[(long)eperm[idx] * 16 + cc];
        float a0 = fmaf(q, k0, x0 * t);
        a0 += __shfl_xor(a0, 1, 16);
        a0 += __shfl_xor(a0, 2, 16);
        a0 += __shfl_xor(a0, 4, 16);
        a0 += __shfl_xor(a0, 8, 16);
        float nm = fmaxf(m, a0);
        float w = __builtin_exp2f(m - nm);
        float p0 = __builtin_exp2f(a0 - nm);
        accd = fmaf(accd, w, p0);
        accv = fmaf(accv, w, p0 * v0);
        acce = fmaf(acce, w, p0 * x0);
        m = nm;
    }
    float inv = 1.f / (accd + 1e-16f);
    tile[wv][lane] = acce * inv;
    float re = 0.f;
#pragma unroll
    for (int i = 0; i < 16; ++i)
        re = fmaf(tile[wv][hh * 16 + i], sWe[i * 64 + lane], re);
    size_t o = (size_t)n * 64 + lane;
    float hv = h[o];
    h[o] = hv + fmaxf(fmaf(accv, inv, re + sn[o]), 0.f);
}

__global__ void k_pool(const float* __restrict__ h, const int* __restrict__ gstart,
                       const float* __restrict__ W1, const float* __restrict__ b1,
                       const float* __restrict__ W2, const float* __restrict__ b2,
                       float* __restrict__ out) {
    int g = blockIdx.x;
    int lane = threadIdx.x & 63, wv = threadIdx.x >> 6;
    int beg = gstart[g], end = gstart[g + 1];
    __shared__ float red[4][64];
    __shared__ float sp[64];
    __shared__ float sh[32];
    float acc = 0.f;
    for (int n = beg + wv; n < end; n += 4) acc += h[(size_t)n * 64 + lane];
    red[wv][lane] = acc;
    __syncthreads();
    if (threadIdx.x < 64) {
        float c = fmaxf((float)(end - beg), 1.f);
        sp[lane] = (red[0][lane] + red[1][lane] + red[2][lane] + red[3][lane]) / c;
    }
    __syncthreads();
    if (threadIdx.x < 32) {
        int t = threadIdx.x;
        float a = b1[t];
#pragma unroll
        for (int i = 0; i < 64; ++i) a = fmaf(sp[i], W1[i * 32 + t], a);
        sh[t] = fmaxf(a, 0.f) * W2[t];
    }
    __syncthreads();
    if (threadIdx.x == 0) {
        float s = b2[0];
#pragma unroll
        for (int i = 0; i < 32; ++i) s += sh[i];
        out[g] = s;
    }
}

extern "C" void kernel_launch(void* const* d_in, const int* in_sizes, int n_in,
                              void* d_out, int out_size, void* d_ws, size_t ws_size,
                              hipStream_t stream) {
    const float* x   = (const float*)d_in[0];
    const int*   ei  = (const int*)d_in[1];
    const float* ea  = (const float*)d_in[2];
    const int*   bat = (const int*)d_in[3];
    const float* Wn  = (const float*)d_in[4];
    const float* bn  = (const float*)d_in[5];
    const float* Wq  = (const float*)d_in[6];
    const float* bq  = (const float*)d_in[7];
    const float* Wk  = (const float*)d_in[8];
    const float* bk  = (const float*)d_in[9];
    const float* Wv  = (const float*)d_in[10];
    const float* bv  = (const float*)d_in[11];
    const float* We  = (const float*)d_in[12];
    const float* Wsk = (const float*)d_in[13];
    const float* bs  = (const float*)d_in[14];
    const float* W1  = (const float*)d_in[15];
    const float* b1  = (const float*)d_in[16];
    const float* W2  = (const float*)d_in[17];
    const float* b2  = (const float*)d_in[18];
    float* out = (float*)d_out;

    const size_t NH = (size_t)Nn * 64;
    float* h    = (float*)d_ws;
    float* qn   = h + NH;                      // fp16 q (uses half the slot)
    float* tq   = h + 2 * NH;                  // fp16 t
    float* sn   = h + 3 * NH;
    __half* kv  = (__half*)(h + 4 * NH);       // N*128 half == NH floats of space
    float* Wqm3 = h + 5 * NH;                  // 3*4096
    float* bqm3 = Wqm3 + 3 * 4096;             // 3*64
    __half* pw  = (__half*)(bqm3 + 3 * 64);    // 3*5*4096 packed fp16 weights
    int* deg       = (int*)(pw + 3 * 5 * 4096);   // N (legacy)
    int* row_ptr   = deg + Nn;                 // N+1
    int* cursor    = row_ptr + Nn + 1;         // N (legacy)
    int* src_perm  = cursor + Nn;              // E
    int* eperm     = src_perm + Ee;            // E (eord in mode 2; eperm legacy)
    int* bsum      = eperm + Ee;               // 256 (legacy)
    int* gstart    = bsum + 256;               // G+1
    char* pe = (char*)(gstart + Gg + 1);
    __half* ea_h = (__half*)(((uintptr_t)pe + 63) & ~(uintptr_t)63);   // E*16 half
    char* pt = (char*)(ea_h + (size_t)Ee * 16);
    unsigned long long* tmp =
        (unsigned long long*)(((uintptr_t)pt + 15) & ~(uintptr_t)15);  // E u64
    size_t need_eah = ((char*)(ea_h + (size_t)Ee * 16)) - (char*)d_ws;
    size_t need_tmp = ((char*)(tmp + Ee)) - (char*)d_ws;
    // CSR-build scratch overlaid on tq/sn (dead until the first qkvt2, which
    // runs after the CSR build completes in stream order). eord uses the
    // legacy eperm slot so it does NOT alias qn16 (needed for k_sqk fusion).
    int* eord    = eperm;                                // E ints (mode 2)
    int* table   = (int*)tq;                             // NBK*NTB ints (~2.4 MB)
    int* bktsz   = (int*)sn;                             // NBK
    int* bktbase = bktsz + 1024;                         // NBK+1
    __half* qn16 = (__half*)qn;
    __half* tq16 = (__half*)tq;
    // mode 2: zero-global-atomic counting-sort CSR build (fast).
    // mode 1: legacy scatter + easort. mode 0: legacy scatter, fp32 ea gather.
    int mode = (ws_size >= need_tmp) ? 2 : (ws_size >= need_eah) ? 1 : 0;

    if (mode == 2) {
        k_cnt<<<NTB, 256, 0, stream>>>(ei, table);
        k_colscan<<<NBK, 256, 0, stream>>>(table, bktsz);
        k_bktscan<<<1, 256, 0, stream>>>(bktsz, bktbase);
        k_binfill<<<NTB, 256, 0, stream>>>(ei, table, bktbase, tmp);
        k_bktB<<<NBK, 256, 0, stream>>>(tmp, bktbase, row_ptr, src_perm, eord);
    } else {
        const int NB = 196;  // ceil(50000/256)
        hipMemsetAsync(deg, 0, Nn * sizeof(int), stream);
        k_hist<<<(Ee + 255) / 256, 256, 0, stream>>>(ei, deg);
        k_scan1<<<NB, 256, 0, stream>>>(deg, row_ptr, bsum);
        k_scan2<<<1, 256, 0, stream>>>(bsum, NB);
        k_scan3<<<(Nn + 256) / 256, 256, 0, stream>>>(row_ptr, bsum);
        hipMemcpyAsync(cursor, row_ptr, Nn * sizeof(int), hipMemcpyDeviceToDevice, stream);
        k_scatter<<<(Ee + 255) / 256, 256, 0, stream>>>(ei, cursor, src_perm, eperm);
        if (mode == 1)
            k_easort<<<((long)Ee * 4 + 255) / 256, 256, 0, stream>>>(ea, eperm, ea_h);
    }
    k_gbound<<<(Nn + 255) / 256, 256, 0, stream>>>(bat, gstart);
    k_wqm3<<<3, 256, 0, stream>>>(Wq, bq, We, Wqm3, bqm3);
    k_pack<<<15, 256, 0, stream>>>(Wq, Wk, Wv, Wqm3, Wsk, pw);

    int nodeBlocks = (Nn + 63) / 64;
    k_encode<<<nodeBlocks, 256, 0, stream>>>(x, Wn, bn, h);
    for (int l = 0; l < 3; ++l) {
        if (l == 0 && mode == 2) {
            // fused: ea gather/convert (edge chain) overlaps layer-0 QKVT
            k_sqk<<<SB2B + nodeBlocks, 256, 0, stream>>>(eord, ea, ea_h,
                    h, pw, bq, bk, bv, bqm3, bs, qn16, kv, tq16, sn);
        } else {
            k_qkvt2<<<nodeBlocks, 256, 0, stream>>>(h, pw + (size_t)l * 5 * 4096,
                    bq + l * 64, bk + l * 64, bv + l * 64,
                    bqm3 + l * 64, bs + l * 64, qn16, kv, tq16, sn);
        }
        if (mode >= 1)
            k_layer8<<<(Nn + 15) / 16, 256, 0, stream>>>(h, qn16, kv, tq16, sn,
                    row_ptr, src_perm, ea_h, We + l * 1024);
        else
            k_layer<<<(Nn + 3) / 4, 256, 0, stream>>>(h, qn16, kv, tq16, sn,
                    row_ptr, src_perm, eperm, ea, We + l * 1024);
    }
    k_pool<<<Gg, 256, 0, stream>>>(h, gstart, W1, b1, W2, b2, out);
}